// Round 5
// baseline (280.556 us; speedup 1.0000x reference)
//
#include <hip/hip_runtime.h>

#define DEVFN __device__ __forceinline__

typedef unsigned short u16;
typedef __attribute__((ext_vector_type(8))) unsigned short u16x8;
typedef __attribute__((ext_vector_type(4))) unsigned short u16x4;
typedef __attribute__((ext_vector_type(8))) __bf16 bf16x8;
typedef __attribute__((ext_vector_type(4))) float f32x4;

// ---------- helpers ----------
DEVFN u16 f2bf_hw(float f) {  // hardware RNE convert (single v_cvt)
    return __builtin_bit_cast(u16, (__bf16)f);
}

DEVFN float bf2f(u16 h) {
    unsigned u = (unsigned)h << 16;
    return __builtin_bit_cast(float, u);
}

DEVFN bf16x8 ldfrag(const u16* p) {
    return __builtin_bit_cast(bf16x8, *(const u16x8*)p);
}

DEVFN f32x4 mfma16(bf16x8 a, bf16x8 b, f32x4 c) {
    return __builtin_amdgcn_mfma_f32_16x16x32_bf16(a, b, c, 0, 0, 0);
}

// async global->LDS, 16B per lane; l must be the wave-uniform base.
// The GLOBAL source address is per-lane (guide §5) -> row-gather OK.
DEVFN void async16(const u16* g, u16* l) {
    __builtin_amdgcn_global_load_lds(
        (const __attribute__((address_space(1))) void*)g,
        (__attribute__((address_space(3))) void*)l, 16, 0, 0);
}

// ---------- fp32->bf16 converts + mask compaction + work-queue init ----------
__global__ __launch_bounds__(256) void conv_all(const float* __restrict__ y,
                                                const float* __restrict__ w0,
                                                const float* __restrict__ w1,
                                                const float* __restrict__ w2,
                                                const float* __restrict__ w3,
                                                u16* __restrict__ yb,
                                                u16* __restrict__ wb,
                                                const int* __restrict__ mask,
                                                int* __restrict__ idx,
                                                int* __restrict__ cnt,
                                                int* __restrict__ kvoff,
                                                int* __restrict__ ctr) {
    const int b = blockIdx.x;
    if (b >= 12288) {
        __shared__ int scnt[8];
        const int wave = threadIdx.x >> 6, lane = threadIdx.x & 63;
        for (int bb = wave; bb < 8; bb += 4) {
            const int* m = mask + bb * 1024;
            int* ib = idx + bb * 1024;
            int base = 0;
            for (int t = 0; t < 16; ++t) {
                const int pos = t * 64 + lane;
                const int valid = (m[pos] == 0) ? 1 : 0;
                const unsigned long long bal = __ballot(valid);
                const int pre = __popcll(bal & ((1ull << lane) - 1ull));
                if (valid) ib[base + pre] = pos;
                base += (int)__popcll(bal);
            }
            if (lane == 0) { cnt[bb] = base; scnt[bb] = base; }
            for (int i = base + lane; i < 1024; i += 64) ib[i] = 0;  // safe pad
        }
        __syncthreads();
        if (threadIdx.x == 0) {
            // KV work-items per batch: ceil(cn/128) m-tiles x 16 n-tiles
            int off = 0;
            kvoff[0] = 0;
            for (int bb = 0; bb < 8; ++bb) {
                off += ((scnt[bb] + 127) >> 7) << 4;
                kvoff[bb + 1] = off;
            }
            *ctr = 0;  // reset work-stealing counter (stream-ordered)
        }
        return;
    }
    const float* src;
    u16* dst;
    int i;
    if (b < 8192) {
        src = y; dst = yb;
        i = b * 1024 + threadIdx.x * 4;
    } else {
        const int g = (b - 8192) >> 10;
        src = g == 0 ? w0 : (g == 1 ? w1 : (g == 2 ? w2 : w3));
        dst = wb + (size_t)g * 1024 * 1024;
        i = ((b - 8192) & 1023) * 1024 + threadIdx.x * 4;
    }
    const float4 v = *(const float4*)&src[i];
    u16x4 o;
    o.x = f2bf_hw(v.x); o.y = f2bf_hw(v.y);
    o.z = f2bf_hw(v.z); o.w = f2bf_hw(v.w);
    *(u16x4*)&dst[i] = o;
}

// ---------- work-stealing Q + compacted-KV GEMM (legacy 128^2 engine) ----------
// Round-5 theory: the 96-KiB-LDS 256-tile kernels run at 1 block/CU ->
// makespan quantizes to 22-us tile "rounds" (round 2: 3x22=66 measured; round
// 4: critical-path CU still 3 alive tiles = 66). Fix = fine quanta + high
// residency + dynamic balance:
//   - engine: round-0 legacy 128x128 tile (56 VGPR, 16 KiB LDS -> 4/CU,
//     measured 687-730 TF effective incl. its bank conflicts)
//   - items: 512 Q-tiles (y @ Wq^T, M=8192 N=1024) + per-batch
//     ceil(cn/128)x16 KV-tiles (y[idx] @ [Wk;Wv]^T, N=2048) via kvoff prefix
//   - grid 1024 persistent blocks, atomicAdd work-stealing (ctr zeroed by
//     conv_all each launch; rocprof replays whole stream incl. conv_all)
// Per-tile arithmetic identical to prior rounds (K ascending 32-chunks) ->
// absmax unchanged.
__global__ __launch_bounds__(256, 4) void gemm_ws(const u16* __restrict__ A,
                                                  const u16* __restrict__ Wq,
                                                  const u16* __restrict__ Wkv,
                                                  const float* __restrict__ bq,
                                                  const float* __restrict__ bk,
                                                  const float* __restrict__ bv,
                                                  u16* __restrict__ qb,
                                                  u16* __restrict__ kb,
                                                  u16* __restrict__ vb,
                                                  const int* __restrict__ idxb,
                                                  const int* __restrict__ kvoff,
                                                  int* __restrict__ ctr) {
    const int K = 1024;
    __shared__ u16 lA[128 * 32];
    __shared__ u16 lB[128 * 32];
    __shared__ int s_item;
    __shared__ int s_kv[9];
    const int tid = threadIdx.x;
    if (tid < 9) s_kv[tid] = kvoff[tid];
    const int wave = tid >> 6, lane = tid & 63;
    const int quad = lane >> 4, l16 = lane & 15;
    const int wm = (wave >> 1) * 64, wn = (wave & 1) * 64;
    const int srow = tid >> 2, scol = (tid & 3) * 8;
    u16* lA0 = &lA[wave * 512];
    u16* lA1 = &lA[2048 + wave * 512];
    u16* lB0 = &lB[wave * 512];
    u16* lB1 = &lB[2048 + wave * 512];
    for (;;) {
        if (tid == 0) s_item = atomicAdd(ctr, 1);
        __syncthreads();  // publishes s_item (and s_kv on first pass)
        const int item = s_item;
        if (item >= 512 + s_kv[8]) return;  // uniform exit
        // ---- decode ----
        int m0, n0, rowbase = 0;
        const u16* Bt;
        const float *bp0, *bp1;
        u16 *cp0, *cp1;
        const int* ib = nullptr;
        if (item < 512) {  // Q: 64 mtiles x 8 ntiles, n-fast
            m0 = (item >> 3) * 128;
            n0 = (item & 7) * 128;
            Bt = Wq; bp0 = bq; bp1 = bq; cp0 = qb; cp1 = qb;
        } else {  // KV: batch via prefix table
            int r = item - 512;
            int bsel = 0;
            while (r >= s_kv[bsel + 1]) ++bsel;  // <=7 uniform iters
            const int local = r - s_kv[bsel];
            m0 = (local >> 4) * 128;
            n0 = (local & 15) * 128;
            rowbase = bsel * 1024;
            ib = idxb + bsel * 1024;
            Bt = Wkv; bp0 = bk; bp1 = bv; cp0 = kb; cp1 = vb;
        }
        int r0 = m0 + srow, r1 = m0 + 64 + srow;
        if (ib) { r0 = ib[r0]; r1 = ib[r1]; }  // gather compacted A rows
        const u16* Ag0 = A + (size_t)(rowbase + r0) * K + scol;
        const u16* Ag1 = A + (size_t)(rowbase + r1) * K + scol;
        const u16* Bg0 = Bt + (size_t)(n0 + srow) * K + scol;
        const u16* Bg1 = Bt + (size_t)(n0 + 64 + srow) * K + scol;
        f32x4 acc[4][4] = {};
        for (int k0 = 0; k0 < K; k0 += 32) {
            __syncthreads();
            async16(Ag0 + k0, lA0);
            async16(Ag1 + k0, lA1);
            async16(Bg0 + k0, lB0);
            async16(Bg1 + k0, lB1);
            __syncthreads();
            bf16x8 af[4], bfr[4];
            #pragma unroll
            for (int i = 0; i < 4; ++i)
                af[i] = ldfrag(&lA[(wm + i * 16 + l16) * 32 + quad * 8]);
            #pragma unroll
            for (int i = 0; i < 4; ++i)
                bfr[i] = ldfrag(&lB[(wn + i * 16 + l16) * 32 + quad * 8]);
            #pragma unroll
            for (int mi = 0; mi < 4; ++mi)
                #pragma unroll
                for (int ni = 0; ni < 4; ++ni)
                    acc[mi][ni] = mfma16(af[mi], bfr[ni], acc[mi][ni]);
        }
        // epilogue: bias + bf16 store; col>>10 selects {q} or {k,v}
        #pragma unroll
        for (int mi = 0; mi < 4; ++mi) {
            #pragma unroll
            for (int ni = 0; ni < 4; ++ni) {
                const int col = n0 + wn + ni * 16 + l16;
                const int cs = col >> 10;
                const int c = col & 1023;
                const float* bp = cs == 0 ? bp0 : bp1;
                u16* cp = cs == 0 ? cp0 : cp1;
                const float bb = bp[c];
                #pragma unroll
                for (int r = 0; r < 4; ++r) {
                    const int row = m0 + wm + mi * 16 + quad * 4 + r;
                    cp[(size_t)(rowbase + row) * 1024 + c] =
                        f2bf_hw(acc[mi][ni][r] + bb);
                }
            }
        }
        // loop: last k-iter drained LDS reads (lgkm before its barrier);
        // next item's staging only starts after the next top barrier.
    }
}

// ---------- pipelined 256x128 GEMM (round-2 kernel, kept for M-proj) ----------
__global__ __launch_bounds__(512, 2) void gemm8b(const u16* __restrict__ A,
                                                 const u16* __restrict__ Bt,
                                                 const float* __restrict__ b0,
                                                 const float* __restrict__ b1,
                                                 const float* __restrict__ b2,
                                                 u16* __restrict__ C0,
                                                 u16* __restrict__ C1,
                                                 u16* __restrict__ C2,
                                                 int K, int NBX) {
    __shared__ u16 lds[2][24576];  // per buf: A @0 (16384), B @16384 (8192)
    const int NT = K >> 6;
    const int tid = threadIdx.x;
    const int wave = tid >> 6, lane = tid & 63;
    const int quad = lane >> 4, l16 = lane & 15;
    const int wm = wave >> 1, wn = wave & 1;
    const int nwg = gridDim.x, cpx = nwg >> 3;
    const int sb = (blockIdx.x & 7) * cpx + (blockIdx.x >> 3);
    const int bx = sb % NBX, by = sb / NBX;
    const int m0 = by * 256, n0 = bx * 128;
    const int sr = lane >> 3, sc = lane & 7;
    const int scs = (sc ^ sr) << 3;
    const u16* Ag = A + (size_t)(m0 + wave * 8 + sr) * K + scs;
    const u16* Bg = Bt + (size_t)(n0 + wave * 8 + sr) * K + scs;
    const size_t rstep = (size_t)64 * K;
    const int swz = (quad ^ (l16 & 7)) << 3;
    const int rofA = (wm * 64 + l16) * 64 + swz;
    const int rofB = (wn * 64 + l16) * 64 + swz;

#define STAGE(gp, lp)                                        \
    do {                                                     \
        async16((gp), (lp) + wave * 512);                    \
        async16((gp) + rstep, (lp) + 4096 + wave * 512);     \
    } while (0)

    f32x4 acc[4][4] = {};

    STAGE(Ag, &lds[0][0]);
    STAGE(Ag + 2 * rstep, &lds[0][8192]);
    STAGE(Bg, &lds[0][16384]);
    STAGE(Ag + 64, &lds[1][0]);
    STAGE(Ag + 2 * rstep + 64, &lds[1][8192]);
    asm volatile("s_waitcnt vmcnt(4)" ::: "memory");
    __builtin_amdgcn_s_barrier();

    for (int t = 0; t < NT; ++t) {
        const int buf = t & 1;
        const u16* Ar = &lds[buf][0];
        const u16* Br = &lds[buf][16384];
        bf16x8 af[4][2], bfr[4][2];
        #pragma unroll
        for (int mi = 0; mi < 4; ++mi) {
            af[mi][0] = ldfrag(Ar + mi * 1024 + rofA);
            af[mi][1] = ldfrag(Ar + mi * 1024 + (rofA ^ 32));
        }
        #pragma unroll
        for (int ni = 0; ni < 2; ++ni) {
            bfr[ni][0] = ldfrag(Br + ni * 1024 + rofB);
            bfr[ni][1] = ldfrag(Br + ni * 1024 + (rofB ^ 32));
        }
        if (t + 1 < NT) STAGE(Bg + (t + 1) * 64, &lds[buf ^ 1][16384]);
        __builtin_amdgcn_s_barrier();
        asm volatile("s_waitcnt lgkmcnt(0)" ::: "memory");
        __builtin_amdgcn_s_setprio(1);
        #pragma unroll
        for (int mi = 0; mi < 4; ++mi)
            #pragma unroll
            for (int ni = 0; ni < 2; ++ni) {
                acc[mi][ni] = mfma16(af[mi][0], bfr[ni][0], acc[mi][ni]);
                acc[mi][ni] = mfma16(af[mi][1], bfr[ni][1], acc[mi][ni]);
            }
        __builtin_amdgcn_s_setprio(0);
        __builtin_amdgcn_s_barrier();
        #pragma unroll
        for (int ni = 2; ni < 4; ++ni) {
            bfr[ni][0] = ldfrag(Br + ni * 1024 + rofB);
            bfr[ni][1] = ldfrag(Br + ni * 1024 + (rofB ^ 32));
        }
        if (t + 2 < NT) {
            STAGE(Ag + (t + 2) * 64, &lds[buf][0]);
            STAGE(Ag + 2 * rstep + (t + 2) * 64, &lds[buf][8192]);
        }
        __builtin_amdgcn_s_barrier();
        asm volatile("s_waitcnt lgkmcnt(0)" ::: "memory");
        __builtin_amdgcn_s_setprio(1);
        #pragma unroll
        for (int mi = 0; mi < 4; ++mi)
            #pragma unroll
            for (int ni = 2; ni < 4; ++ni) {
                acc[mi][ni] = mfma16(af[mi][0], bfr[ni][0], acc[mi][ni]);
                acc[mi][ni] = mfma16(af[mi][1], bfr[ni][1], acc[mi][ni]);
            }
        __builtin_amdgcn_s_setprio(0);
        if (t < NT - 2)
            asm volatile("s_waitcnt vmcnt(4)" ::: "memory");
        else
            asm volatile("s_waitcnt vmcnt(0)" ::: "memory");
        __builtin_amdgcn_s_barrier();
    }
#undef STAGE
    const int wrow = m0 + wm * 64 + quad * 4;
    #pragma unroll
    for (int ni = 0; ni < 4; ++ni) {
        const int col = n0 + wn * 64 + ni * 16 + l16;
        const int cs = col >> 10;
        const int c = col & 1023;
        const float* bp = cs == 0 ? b0 : (cs == 1 ? b1 : b2);
        u16* cp = cs == 0 ? C0 : (cs == 1 ? C1 : C2);
        const float bb = bp[c];
        #pragma unroll
        for (int mi = 0; mi < 4; ++mi)
            #pragma unroll
            for (int r = 0; r < 4; ++r) {
                const int row = wrow + mi * 16 + r;
                cp[(size_t)row * 1024 + c] = f2bf_hw(acc[mi][ni][r] + bb);
            }
    }
}

// ---------- flash attention over COMPACTED K/V (dense rows) ----------
__global__ __launch_bounds__(256) void attn(const u16* __restrict__ qb,
                                            const u16* __restrict__ kb,
                                            const u16* __restrict__ vb,
                                            const int* __restrict__ cntb,
                                            u16* __restrict__ attb) {
    const int lin = blockIdx.x;
    const int xcd = lin & 7, slot = lin >> 3;          // slot 0..127
    const int bh = xcd * 16 + (slot >> 3);
    const int q0 = (slot & 7) * 128;
    const int bb = bh >> 4, h = bh & 15;
    const int tid = threadIdx.x, wave = tid >> 6, lane = tid & 63;
    const int quad = lane >> 4, l16 = lane & 15;
    __shared__ u16 lK[64 * 72];
    __shared__ u16 lV[64 * 72];
    __shared__ u16 lP[128 * 72];

    const int cn = cntb[bb];
    const int kEnd = (cn + 63) & ~63;

    bf16x8 aq[2][2];
    #pragma unroll
    for (int rg = 0; rg < 2; ++rg) {
        const int qrow = q0 + wave * 32 + rg * 16 + l16;
        const u16* qp = qb + (size_t)(bb * 1024 + qrow) * 1024 + h * 64 + quad * 8;
        aq[rg][0] = ldfrag(qp);
        aq[rg][1] = ldfrag(qp + 32);
    }

    f32x4 o[2][4] = {};
    float ps_acc[2][4] = {};

    const int srow = tid >> 3, scol = (tid & 7) * 8;
    const u16* kbase = kb + (size_t)(bb * 1024) * 1024 + h * 64 + scol;
    const u16* vbase = vb + (size_t)(bb * 1024) * 1024 + h * 64 + scol;

    u16x8 nk0 = *(const u16x8*)(kbase + (size_t)srow * 1024);
    u16x8 nk1 = *(const u16x8*)(kbase + (size_t)(srow + 32) * 1024);
    u16x8 nv0 = *(const u16x8*)(vbase + (size_t)srow * 1024);
    u16x8 nv1 = *(const u16x8*)(vbase + (size_t)(srow + 32) * 1024);

    const float C = 0.18033688011112043f;  // 0.125 * log2(e)

    for (int kt = 0; kt < kEnd; kt += 64) {
        __syncthreads();
        *(u16x8*)&lK[srow * 72 + scol] = nk0;
        *(u16x8*)&lK[(srow + 32) * 72 + scol] = nk1;
        #pragma unroll
        for (int j = 0; j < 8; ++j) {
            lV[(scol + j) * 72 + srow] = nv0[j];
            lV[(scol + j) * 72 + srow + 32] = nv1[j];
        }
        __syncthreads();
        const int ktn = kt + 64;
        if (ktn < kEnd) {
            nk0 = *(const u16x8*)(kbase + (size_t)(ktn + srow) * 1024);
            nk1 = *(const u16x8*)(kbase + (size_t)(ktn + srow + 32) * 1024);
            nv0 = *(const u16x8*)(vbase + (size_t)(ktn + srow) * 1024);
            nv1 = *(const u16x8*)(vbase + (size_t)(ktn + srow + 32) * 1024);
        }

        bf16x8 kf[4][2];
        #pragma unroll
        for (int n = 0; n < 4; ++n) {
            kf[n][0] = ldfrag(&lK[(n * 16 + l16) * 72 + quad * 8]);
            kf[n][1] = ldfrag(&lK[(n * 16 + l16) * 72 + 32 + quad * 8]);
        }
        f32x4 s[2][4];
        #pragma unroll
        for (int rg = 0; rg < 2; ++rg)
            #pragma unroll
            for (int n = 0; n < 4; ++n) {
                f32x4 t = {};
                t = mfma16(aq[rg][0], kf[n][0], t);
                t = mfma16(aq[rg][1], kf[n][1], t);
                s[rg][n] = t;
            }
        float bias[4];
        #pragma unroll
        for (int n = 0; n < 4; ++n)
            bias[n] = (kt + n * 16 + l16 < cn) ? 0.0f : -1e9f;
        #pragma unroll
        for (int rg = 0; rg < 2; ++rg)
            #pragma unroll
            for (int n = 0; n < 4; ++n)
                #pragma unroll
                for (int r = 0; r < 4; ++r) {
                    const float p =
                        __builtin_amdgcn_exp2f(__builtin_fmaf(s[rg][n][r], C, bias[n]));
                    ps_acc[rg][r] += p;
                    lP[(wave * 32 + rg * 16 + quad * 4 + r) * 72 + n * 16 + l16] =
                        f2bf_hw(p);
                }
        __asm__ __volatile__("s_waitcnt lgkmcnt(0)" ::: "memory");
        bf16x8 ap[2][2];
        #pragma unroll
        for (int rg = 0; rg < 2; ++rg) {
            ap[rg][0] = ldfrag(&lP[(wave * 32 + rg * 16 + l16) * 72 + quad * 8]);
            ap[rg][1] = ldfrag(&lP[(wave * 32 + rg * 16 + l16) * 72 + 32 + quad * 8]);
        }
        bf16x8 vf[4][2];
        #pragma unroll
        for (int ni = 0; ni < 4; ++ni) {
            vf[ni][0] = ldfrag(&lV[(ni * 16 + l16) * 72 + quad * 8]);
            vf[ni][1] = ldfrag(&lV[(ni * 16 + l16) * 72 + 32 + quad * 8]);
        }
        #pragma unroll
        for (int rg = 0; rg < 2; ++rg)
            #pragma unroll
            for (int ni = 0; ni < 4; ++ni) {
                o[rg][ni] = mfma16(ap[rg][0], vf[ni][0], o[rg][ni]);
                o[rg][ni] = mfma16(ap[rg][1], vf[ni][1], o[rg][ni]);
            }
    }
    #pragma unroll
    for (int off = 1; off < 16; off <<= 1)
        #pragma unroll
        for (int rg = 0; rg < 2; ++rg)
            #pragma unroll
            for (int r = 0; r < 4; ++r)
                ps_acc[rg][r] += __shfl_xor(ps_acc[rg][r], off);
    float rl[2][4];
    #pragma unroll
    for (int rg = 0; rg < 2; ++rg)
        #pragma unroll
        for (int r = 0; r < 4; ++r) rl[rg][r] = 1.f / ps_acc[rg][r];
    #pragma unroll
    for (int rg = 0; rg < 2; ++rg)
        #pragma unroll
        for (int ni = 0; ni < 4; ++ni)
            #pragma unroll
            for (int r = 0; r < 4; ++r) {
                const int row = q0 + wave * 32 + rg * 16 + quad * 4 + r;
                attb[(size_t)(bb * 1024 + row) * 1024 + h * 64 + ni * 16 + l16] =
                    f2bf_hw(o[rg][ni][r] * rl[rg][r]);
            }
}

// ---------- residual (bf16 y) + LayerNorm ----------
__global__ __launch_bounds__(256) void ln_res(const u16* __restrict__ ybf,
                                              const u16* __restrict__ xpb,
                                              const float* __restrict__ a2,
                                              const float* __restrict__ b2,
                                              float* __restrict__ out) {
    const int row = blockIdx.x, tid = threadIdx.x;
    const size_t base = (size_t)row * 1024;
    const int j = tid * 4;
    const u16x4 yv = *(const u16x4*)&ybf[base + j];
    const u16x4 xv = *(const u16x4*)&xpb[base + j];
    float x[4] = {bf2f(yv.x) + bf2f(xv.x), bf2f(yv.y) + bf2f(xv.y),
                  bf2f(yv.z) + bf2f(xv.z), bf2f(yv.w) + bf2f(xv.w)};
    float s = 0.f, ss = 0.f;
    #pragma unroll
    for (int i = 0; i < 4; ++i) { s += x[i]; ss += x[i] * x[i]; }
    #pragma unroll
    for (int off = 1; off < 64; off <<= 1) {
        s += __shfl_xor(s, off);
        ss += __shfl_xor(ss, off);
    }
    __shared__ float rs[4], rss[4];
    const int wave = tid >> 6, lane = tid & 63;
    if (lane == 0) { rs[wave] = s; rss[wave] = ss; }
    __syncthreads();
    s = rs[0] + rs[1] + rs[2] + rs[3];
    ss = rss[0] + rss[1] + rss[2] + rss[3];
    const float mean = s * (1.f / 1024.f);
    float var = (ss - s * mean) * (1.f / 1023.f);
    var = fmaxf(var, 0.f);
    const float inv = 1.f / (sqrtf(var) + 1e-6f);
    const float4 av = *(const float4*)&a2[j];
    const float4 bv = *(const float4*)&b2[j];
    float4 ov;
    ov.x = av.x * (x[0] - mean) * inv + bv.x;
    ov.y = av.y * (x[1] - mean) * inv + bv.y;
    ov.z = av.z * (x[2] - mean) * inv + bv.z;
    ov.w = av.w * (x[3] - mean) * inv + bv.w;
    *(float4*)&out[base + j] = ov;
}

extern "C" void kernel_launch(void* const* d_in, const int* in_sizes, int n_in,
                              void* d_out, int out_size, void* d_ws, size_t ws_size,
                              hipStream_t stream) {
    (void)in_sizes; (void)n_in; (void)out_size;
    const float* y   = (const float*)d_in[0];
    const int*   msk = (const int*)d_in[1];
    const float* Wq  = (const float*)d_in[2];
    const float* bq  = (const float*)d_in[3];
    const float* Wk  = (const float*)d_in[4];
    const float* bkb = (const float*)d_in[5];
    const float* Wv  = (const float*)d_in[6];
    const float* bv  = (const float*)d_in[7];
    const float* Wm  = (const float*)d_in[8];
    const float* bm  = (const float*)d_in[9];
    const float* a2  = (const float*)d_in[10];
    const float* b2  = (const float*)d_in[11];
    float* out = (float*)d_out;

    char* ws = (char*)d_ws;
    const size_t MB = 1u << 20;
    if (ws_size < 72 * MB) return;  // need 72 MB of scratch
    u16* yb  = (u16*)(ws);             // 16 MB, stays LIVE (ln_res reads it)
    u16* wqb = (u16*)(ws + 16 * MB);   // wq/wk/wv/wm contiguous (8 MB)
    u16* wmb = (u16*)(ws + 22 * MB);
    u16* qb  = (u16*)(ws + 24 * MB);   // 16 MB (reused as bf16 xp after attn)
    u16* kb  = (u16*)(ws + 40 * MB);   // 16 MB
    u16* vb  = (u16*)(ws + 56 * MB);   // 16 MB (attn reads it live)
    u16* xpb  = qb;   // qb dead after attn

    int* idxb  = (int*)d_out;                      // 8 x 1024 ints
    int* cntb  = idxb + 8192;                      // 8 ints
    int* kvoffb = idxb + 8200;                     // 9 ints (prefix table)
    int* ctrb  = idxb + 8212;                      // 1 int (work counter)
    u16* attb = (u16*)((char*)d_out + 16 * MB);    // 16 MB

    conv_all<<<12289, 256, 0, stream>>>(y, Wq, Wk, Wv, Wm, yb, wqb,
                                        msk, idxb, cntb, kvoffb, ctrb);

    // work-stealing Q + compacted-KV GEMM: 1024 persistent blocks (4/CU),
    // items = 512 Q-tiles + dynamic KV-tiles. Wkv = wqb + 1M u16.
    gemm_ws<<<dim3(1024), 256, 0, stream>>>(
        yb, wqb, wqb + 1024 * 1024, bq, bkb, bv, qb, kb, vb,
        idxb, kvoffb, ctrb);

    attn<<<dim3(1024), 256, 0, stream>>>(qb, kb, vb, cntb, attb);

    // M-proj: M=8192, N=1024, tile 256x128 -> 32x8 = 256 blocks = 1/CU
    gemm8b<<<dim3(256), 512, 0, stream>>>(
        attb, wmb, bm, bm, bm, xpb, xpb, xpb, 1024, 8);

    ln_res<<<8192, 256, 0, stream>>>(yb, xpb, a2, b2, out);
}

// Round 6
// 270.721 us; speedup vs baseline: 1.0363x; 1.0363x over previous
//
#include <hip/hip_runtime.h>

#define DEVFN __device__ __forceinline__

typedef unsigned short u16;
typedef __attribute__((ext_vector_type(8))) unsigned short u16x8;
typedef __attribute__((ext_vector_type(4))) unsigned short u16x4;
typedef __attribute__((ext_vector_type(8))) __bf16 bf16x8;
typedef __attribute__((ext_vector_type(4))) float f32x4;

// ---------- helpers ----------
DEVFN u16 f2bf_hw(float f) {  // hardware RNE convert (single v_cvt)
    return __builtin_bit_cast(u16, (__bf16)f);
}

DEVFN float bf2f(u16 h) {
    unsigned u = (unsigned)h << 16;
    return __builtin_bit_cast(float, u);
}

DEVFN bf16x8 ldfrag(const u16* p) {
    return __builtin_bit_cast(bf16x8, *(const u16x8*)p);
}

DEVFN f32x4 mfma16(bf16x8 a, bf16x8 b, f32x4 c) {
    return __builtin_amdgcn_mfma_f32_16x16x32_bf16(a, b, c, 0, 0, 0);
}

// async global->LDS, 16B per lane; l must be the wave-uniform base.
// The GLOBAL source address is per-lane (guide §5) -> row-gather OK.
DEVFN void async16(const u16* g, u16* l) {
    __builtin_amdgcn_global_load_lds(
        (const __attribute__((address_space(1))) void*)g,
        (__attribute__((address_space(3))) void*)l, 16, 0, 0);
}

// ---------- fp32->bf16 converts + mask compaction, ONE dispatch ----------
__global__ __launch_bounds__(256) void conv_all(const float* __restrict__ y,
                                                const float* __restrict__ w0,
                                                const float* __restrict__ w1,
                                                const float* __restrict__ w2,
                                                const float* __restrict__ w3,
                                                u16* __restrict__ yb,
                                                u16* __restrict__ wb,
                                                const int* __restrict__ mask,
                                                int* __restrict__ idx,
                                                int* __restrict__ cnt) {
    const int b = blockIdx.x;
    if (b >= 12288) {
        const int wave = threadIdx.x >> 6, lane = threadIdx.x & 63;
        for (int bb = wave; bb < 8; bb += 4) {
            const int* m = mask + bb * 1024;
            int* ib = idx + bb * 1024;
            int base = 0;
            for (int t = 0; t < 16; ++t) {
                const int pos = t * 64 + lane;
                const int valid = (m[pos] == 0) ? 1 : 0;
                const unsigned long long bal = __ballot(valid);
                const int pre = __popcll(bal & ((1ull << lane) - 1ull));
                if (valid) ib[base + pre] = pos;
                base += (int)__popcll(bal);
            }
            if (lane == 0) cnt[bb] = base;
            for (int i = base + lane; i < 1024; i += 64) ib[i] = 0;  // safe pad
        }
        return;
    }
    const float* src;
    u16* dst;
    int i;
    if (b < 8192) {
        src = y; dst = yb;
        i = b * 1024 + threadIdx.x * 4;
    } else {
        const int g = (b - 8192) >> 10;
        src = g == 0 ? w0 : (g == 1 ? w1 : (g == 2 ? w2 : w3));
        dst = wb + (size_t)g * 1024 * 1024;
        i = ((b - 8192) & 1023) * 1024 + threadIdx.x * 4;
    }
    const float4 v = *(const float4*)&src[i];
    u16x4 o;
    o.x = f2bf_hw(v.x); o.y = f2bf_hw(v.y);
    o.z = f2bf_hw(v.z); o.w = f2bf_hw(v.w);
    *(u16x4*)&dst[i] = o;
}

// ---------- fused Q + compacted-KV GEMM, 2 blocks/CU (80 KiB LDS) ----------
// Round-6: round-4's 66 us == 3 sequential 22-us tile-rounds at 1 block/CU
// (96 KiB LDS, alive tiles ~520-560 > 512). Work-stealing is ruled out (r5:
// steal-order destroys L2 locality, +44% per tile). Lever = 2 blocks/CU:
// B single-buffered -> LDS = 2xA[256][64] (64 KiB) + B[128][64] (16 KiB)
// = 80 KiB exactly -> 2 resident blocks, concurrency 512 >= alive.
//
// Tile structure (WAR-GUARANTEED ledger, no timing arguments):
//  p1: ALL 16 ds_reads (af mi0-3 x2kh, bfr ni0-3 x2kh); barrier; lgkm(0);
//      MFMA mi x ni01 (16); barrier   <- this barrier proves every wave
//      executed its lgkm(0), i.e. ALL A(t)/B(t) LDS reads are complete.
//  p2: stage B(t+1) (2 gloads, overwrites B(t): safe by p1's trailing
//      barrier) + stage A(t+2) (4 gloads into buf(t): A(t) reads done same
//      way; A(t+1) lives in buf^1, untouched); MFMA mi x ni23 (16);
//      vmcnt(4)  <- outstanding issue order [A(t+1)x4 from p2(t-1)? drained
//      at end of t-1][B(t+1)x2, A(t+2)x4]: leaves exactly A(t+2), so
//      A(t+1) AND B(t+1) are resident before t+1's p1 reads; barrier.
//  Tail t>=NT-2: vmcnt(0). Prologue: A(0),B(0),A(1) -> vmcnt(4) leaves A(1).
// Decode identical to round 4:
//   blocks 0..255  : Q  = y      @ Wq^T  (M=8192, N=1024)
//   blocks 256..767: KV = y[idx] @ [Wk;Wv]^T (per-batch M=ceil256(cn),
//                    N=2048; A rows gathered via per-lane gload_lds source;
//                    dead blocks exit on cnt)
// K ascending in 32-chunks; per-cell accumulation order identical to all
// prior rounds -> absmax unchanged (bit-identical).
__global__ __launch_bounds__(512, 2) void gemm_qkv(const u16* __restrict__ A,
                                                   const u16* __restrict__ Wq,
                                                   const u16* __restrict__ Wkv,
                                                   const float* __restrict__ bq,
                                                   const float* __restrict__ bk,
                                                   const float* __restrict__ bv,
                                                   u16* __restrict__ qb,
                                                   u16* __restrict__ kb,
                                                   u16* __restrict__ vb,
                                                   const int* __restrict__ idxb,
                                                   const int* __restrict__ cntb) {
    const int K = 1024;
    __shared__ u16 lds[40960];  // A dbuf [2][16384] @0; B single @32768 (8192)
    const int tid = threadIdx.x;
    const int wave = tid >> 6, lane = tid & 63;
    const int quad = lane >> 4, l16 = lane & 15;
    const int wm = wave >> 1, wn = wave & 1;
    // XCD-bijective chunked swizzle (768 % 8 == 0)
    const int cpx = gridDim.x >> 3;
    const int sb = (blockIdx.x & 7) * cpx + (blockIdx.x >> 3);
    // ---- role decode (same as round 4) ----
    int m0, n0, rowbase;
    const u16* Bt;
    const float *bp0, *bp1;
    u16 *cp0, *cp1;
    const int* ib = nullptr;
    if (sb < 256) {  // Q: 32 mb x 8 nb, n-fast
        m0 = (sb >> 3) * 256;
        n0 = (sb & 7) * 128;
        rowbase = 0;
        Bt = Wq; bp0 = bq; bp1 = bq; cp0 = qb; cp1 = qb;
    } else {  // KV: b x mb x nb (nb fastest for A-panel L2 reuse)
        const int t = sb - 256;
        const int nb = t & 15, mb = (t >> 4) & 3, b = t >> 6;
        const int cn = cntb[b];
        const int pc = (cn + 255) & ~255;  // ceil256; attn reads <= pc rows
        m0 = mb * 256;
        if (m0 >= pc) return;  // dead block
        n0 = nb * 128;
        rowbase = b * 1024;
        ib = idxb + b * 1024;
        Bt = Wkv; bp0 = bk; bp1 = bv; cp0 = kb; cp1 = vb;
    }
    // ---- per-lane staged A rows (4 row-groups: +0,+64,+128,+192) ----
    const int sr = lane >> 3, sc = lane & 7;
    const int scs = (sc ^ sr) << 3;  // pre-swizzled k-slot of the source row
    const int ar = m0 + wave * 8 + sr;
    int r0 = ar, r1 = ar + 64, r2 = ar + 128, r3 = ar + 192;
    if (ib) { r0 = ib[r0]; r1 = ib[r1]; r2 = ib[r2]; r3 = ib[r3]; }
    const u16* As0 = A + (size_t)(rowbase + r0) * K + scs;
    const u16* As1 = A + (size_t)(rowbase + r1) * K + scs;
    const u16* As2 = A + (size_t)(rowbase + r2) * K + scs;
    const u16* As3 = A + (size_t)(rowbase + r3) * K + scs;
    const u16* Bs0 = Bt + (size_t)(n0 + wave * 8 + sr) * K + scs;
    const u16* Bs1 = Bs0 + (size_t)64 * K;
    // read-side swizzled offsets (u16 units); kh=1 frag = rof ^ 32
    const int swz = (quad ^ (l16 & 7)) << 3;
    const int rofA = (wm * 64 + l16) * 64 + swz;
    const int rofB = (wn * 64 + l16) * 64 + swz;

#define STA(off, bf)                                                  \
    do {                                                              \
        async16(As0 + (off), &lds[(bf) * 16384] + wave * 512);        \
        async16(As1 + (off), &lds[(bf) * 16384 + 4096] + wave * 512); \
        async16(As2 + (off), &lds[(bf) * 16384 + 8192] + wave * 512); \
        async16(As3 + (off), &lds[(bf) * 16384 + 12288] + wave * 512);\
    } while (0)
#define STB(off)                                           \
    do {                                                   \
        async16(Bs0 + (off), &lds[32768] + wave * 512);    \
        async16(Bs1 + (off), &lds[36864] + wave * 512);    \
    } while (0)

    f32x4 acc[4][4] = {};
    const int NT = K >> 6;

    // prologue: A(0) 4, B(0) 2, A(1) 4; vmcnt(4) -> t0 resident (A(1) flies)
    STA(0, 0);
    STB(0);
    STA(64, 1);
    asm volatile("s_waitcnt vmcnt(4)" ::: "memory");
    __builtin_amdgcn_s_barrier();

    for (int t = 0; t < NT; ++t) {
        const int buf = t & 1;
        const u16* Ar = &lds[buf * 16384];
        const u16* Br = &lds[32768];
        bf16x8 af[4][2], bfr[4][2];
        // ---- p1: ALL ds_reads, then MFMA on ni0-1 ----
        #pragma unroll
        for (int mi = 0; mi < 4; ++mi) {
            af[mi][0] = ldfrag(Ar + mi * 1024 + rofA);
            af[mi][1] = ldfrag(Ar + mi * 1024 + (rofA ^ 32));
        }
        #pragma unroll
        for (int ni = 0; ni < 4; ++ni) {
            bfr[ni][0] = ldfrag(Br + ni * 1024 + rofB);
            bfr[ni][1] = ldfrag(Br + ni * 1024 + (rofB ^ 32));
        }
        __builtin_amdgcn_s_barrier();
        asm volatile("s_waitcnt lgkmcnt(0)" ::: "memory");
        __builtin_amdgcn_s_setprio(1);
        #pragma unroll
        for (int mi = 0; mi < 4; ++mi)
            #pragma unroll
            for (int ni = 0; ni < 2; ++ni) {
                acc[mi][ni] = mfma16(af[mi][0], bfr[ni][0], acc[mi][ni]);
                acc[mi][ni] = mfma16(af[mi][1], bfr[ni][1], acc[mi][ni]);
            }
        __builtin_amdgcn_s_setprio(0);
        // trailing barrier: every wave is past its lgkm(0) -> ALL LDS reads
        // of tile t (A and B) are complete; staging below is WAR-safe.
        __builtin_amdgcn_s_barrier();
        // ---- p2: stage B(t+1) + A(t+2), MFMA on ni2-3 ----
        if (t + 1 < NT) STB((t + 1) * 64);
        if (t + 2 < NT) STA((t + 2) * 64, buf);
        __builtin_amdgcn_s_setprio(1);
        #pragma unroll
        for (int mi = 0; mi < 4; ++mi)
            #pragma unroll
            for (int ni = 2; ni < 4; ++ni) {
                acc[mi][ni] = mfma16(af[mi][0], bfr[ni][0], acc[mi][ni]);
                acc[mi][ni] = mfma16(af[mi][1], bfr[ni][1], acc[mi][ni]);
            }
        __builtin_amdgcn_s_setprio(0);
        if (t < NT - 2)
            asm volatile("s_waitcnt vmcnt(4)" ::: "memory");
        else
            asm volatile("s_waitcnt vmcnt(0)" ::: "memory");
        __builtin_amdgcn_s_barrier();
    }
#undef STA
#undef STB
    // epilogue: bias + bf16 store; col>>10 selects {q} or {k,v}
    const int wrow = m0 + wm * 64 + quad * 4;
    #pragma unroll
    for (int ni = 0; ni < 4; ++ni) {
        const int col = n0 + wn * 64 + ni * 16 + l16;
        const int cs = col >> 10;
        const int c = col & 1023;
        const float* bp = cs == 0 ? bp0 : bp1;
        u16* cp = cs == 0 ? cp0 : cp1;
        const float bb = bp[c];
        #pragma unroll
        for (int mi = 0; mi < 4; ++mi)
            #pragma unroll
            for (int r = 0; r < 4; ++r) {
                const int row = rowbase + wrow + mi * 16 + r;
                cp[(size_t)row * 1024 + c] = f2bf_hw(acc[mi][ni][r] + bb);
            }
    }
}

// ---------- pipelined 256x128 GEMM (round-2 kernel, kept for M-proj) ----------
__global__ __launch_bounds__(512, 2) void gemm8b(const u16* __restrict__ A,
                                                 const u16* __restrict__ Bt,
                                                 const float* __restrict__ b0,
                                                 const float* __restrict__ b1,
                                                 const float* __restrict__ b2,
                                                 u16* __restrict__ C0,
                                                 u16* __restrict__ C1,
                                                 u16* __restrict__ C2,
                                                 int K, int NBX) {
    __shared__ u16 lds[2][24576];  // per buf: A @0 (16384), B @16384 (8192)
    const int NT = K >> 6;
    const int tid = threadIdx.x;
    const int wave = tid >> 6, lane = tid & 63;
    const int quad = lane >> 4, l16 = lane & 15;
    const int wm = wave >> 1, wn = wave & 1;
    const int nwg = gridDim.x, cpx = nwg >> 3;
    const int sb = (blockIdx.x & 7) * cpx + (blockIdx.x >> 3);
    const int bx = sb % NBX, by = sb / NBX;
    const int m0 = by * 256, n0 = bx * 128;
    const int sr = lane >> 3, sc = lane & 7;
    const int scs = (sc ^ sr) << 3;
    const u16* Ag = A + (size_t)(m0 + wave * 8 + sr) * K + scs;
    const u16* Bg = Bt + (size_t)(n0 + wave * 8 + sr) * K + scs;
    const size_t rstep = (size_t)64 * K;
    const int swz = (quad ^ (l16 & 7)) << 3;
    const int rofA = (wm * 64 + l16) * 64 + swz;
    const int rofB = (wn * 64 + l16) * 64 + swz;

#define STAGE(gp, lp)                                        \
    do {                                                     \
        async16((gp), (lp) + wave * 512);                    \
        async16((gp) + rstep, (lp) + 4096 + wave * 512);     \
    } while (0)

    f32x4 acc[4][4] = {};

    STAGE(Ag, &lds[0][0]);
    STAGE(Ag + 2 * rstep, &lds[0][8192]);
    STAGE(Bg, &lds[0][16384]);
    STAGE(Ag + 64, &lds[1][0]);
    STAGE(Ag + 2 * rstep + 64, &lds[1][8192]);
    asm volatile("s_waitcnt vmcnt(4)" ::: "memory");
    __builtin_amdgcn_s_barrier();

    for (int t = 0; t < NT; ++t) {
        const int buf = t & 1;
        const u16* Ar = &lds[buf][0];
        const u16* Br = &lds[buf][16384];
        bf16x8 af[4][2], bfr[4][2];
        #pragma unroll
        for (int mi = 0; mi < 4; ++mi) {
            af[mi][0] = ldfrag(Ar + mi * 1024 + rofA);
            af[mi][1] = ldfrag(Ar + mi * 1024 + (rofA ^ 32));
        }
        #pragma unroll
        for (int ni = 0; ni < 2; ++ni) {
            bfr[ni][0] = ldfrag(Br + ni * 1024 + rofB);
            bfr[ni][1] = ldfrag(Br + ni * 1024 + (rofB ^ 32));
        }
        if (t + 1 < NT) STAGE(Bg + (t + 1) * 64, &lds[buf ^ 1][16384]);
        __builtin_amdgcn_s_barrier();
        asm volatile("s_waitcnt lgkmcnt(0)" ::: "memory");
        __builtin_amdgcn_s_setprio(1);
        #pragma unroll
        for (int mi = 0; mi < 4; ++mi)
            #pragma unroll
            for (int ni = 0; ni < 2; ++ni) {
                acc[mi][ni] = mfma16(af[mi][0], bfr[ni][0], acc[mi][ni]);
                acc[mi][ni] = mfma16(af[mi][1], bfr[ni][1], acc[mi][ni]);
            }
        __builtin_amdgcn_s_setprio(0);
        __builtin_amdgcn_s_barrier();
        #pragma unroll
        for (int ni = 2; ni < 4; ++ni) {
            bfr[ni][0] = ldfrag(Br + ni * 1024 + rofB);
            bfr[ni][1] = ldfrag(Br + ni * 1024 + (rofB ^ 32));
        }
        if (t + 2 < NT) {
            STAGE(Ag + (t + 2) * 64, &lds[buf][0]);
            STAGE(Ag + 2 * rstep + (t + 2) * 64, &lds[buf][8192]);
        }
        __builtin_amdgcn_s_barrier();
        asm volatile("s_waitcnt lgkmcnt(0)" ::: "memory");
        __builtin_amdgcn_s_setprio(1);
        #pragma unroll
        for (int mi = 0; mi < 4; ++mi)
            #pragma unroll
            for (int ni = 2; ni < 4; ++ni) {
                acc[mi][ni] = mfma16(af[mi][0], bfr[ni][0], acc[mi][ni]);
                acc[mi][ni] = mfma16(af[mi][1], bfr[ni][1], acc[mi][ni]);
            }
        __builtin_amdgcn_s_setprio(0);
        if (t < NT - 2)
            asm volatile("s_waitcnt vmcnt(4)" ::: "memory");
        else
            asm volatile("s_waitcnt vmcnt(0)" ::: "memory");
        __builtin_amdgcn_s_barrier();
    }
#undef STAGE
    const int wrow = m0 + wm * 64 + quad * 4;
    #pragma unroll
    for (int ni = 0; ni < 4; ++ni) {
        const int col = n0 + wn * 64 + ni * 16 + l16;
        const int cs = col >> 10;
        const int c = col & 1023;
        const float* bp = cs == 0 ? b0 : (cs == 1 ? b1 : b2);
        u16* cp = cs == 0 ? C0 : (cs == 1 ? C1 : C2);
        const float bb = bp[c];
        #pragma unroll
        for (int mi = 0; mi < 4; ++mi)
            #pragma unroll
            for (int r = 0; r < 4; ++r) {
                const int row = wrow + mi * 16 + r;
                cp[(size_t)row * 1024 + c] = f2bf_hw(acc[mi][ni][r] + bb);
            }
    }
}

// ---------- flash attention over COMPACTED K/V (dense rows) ----------
__global__ __launch_bounds__(256) void attn(const u16* __restrict__ qb,
                                            const u16* __restrict__ kb,
                                            const u16* __restrict__ vb,
                                            const int* __restrict__ cntb,
                                            u16* __restrict__ attb) {
    const int lin = blockIdx.x;
    const int xcd = lin & 7, slot = lin >> 3;          // slot 0..127
    const int bh = xcd * 16 + (slot >> 3);
    const int q0 = (slot & 7) * 128;
    const int bb = bh >> 4, h = bh & 15;
    const int tid = threadIdx.x, wave = tid >> 6, lane = tid & 63;
    const int quad = lane >> 4, l16 = lane & 15;
    __shared__ u16 lK[64 * 72];
    __shared__ u16 lV[64 * 72];
    __shared__ u16 lP[128 * 72];

    const int cn = cntb[bb];
    const int kEnd = (cn + 63) & ~63;

    bf16x8 aq[2][2];
    #pragma unroll
    for (int rg = 0; rg < 2; ++rg) {
        const int qrow = q0 + wave * 32 + rg * 16 + l16;
        const u16* qp = qb + (size_t)(bb * 1024 + qrow) * 1024 + h * 64 + quad * 8;
        aq[rg][0] = ldfrag(qp);
        aq[rg][1] = ldfrag(qp + 32);
    }

    f32x4 o[2][4] = {};
    float ps_acc[2][4] = {};

    const int srow = tid >> 3, scol = (tid & 7) * 8;
    const u16* kbase = kb + (size_t)(bb * 1024) * 1024 + h * 64 + scol;
    const u16* vbase = vb + (size_t)(bb * 1024) * 1024 + h * 64 + scol;

    u16x8 nk0 = *(const u16x8*)(kbase + (size_t)srow * 1024);
    u16x8 nk1 = *(const u16x8*)(kbase + (size_t)(srow + 32) * 1024);
    u16x8 nv0 = *(const u16x8*)(vbase + (size_t)srow * 1024);
    u16x8 nv1 = *(const u16x8*)(vbase + (size_t)(srow + 32) * 1024);

    const float C = 0.18033688011112043f;  // 0.125 * log2(e)

    for (int kt = 0; kt < kEnd; kt += 64) {
        __syncthreads();
        *(u16x8*)&lK[srow * 72 + scol] = nk0;
        *(u16x8*)&lK[(srow + 32) * 72 + scol] = nk1;
        #pragma unroll
        for (int j = 0; j < 8; ++j) {
            lV[(scol + j) * 72 + srow] = nv0[j];
            lV[(scol + j) * 72 + srow + 32] = nv1[j];
        }
        __syncthreads();
        const int ktn = kt + 64;
        if (ktn < kEnd) {
            nk0 = *(const u16x8*)(kbase + (size_t)(ktn + srow) * 1024);
            nk1 = *(const u16x8*)(kbase + (size_t)(ktn + srow + 32) * 1024);
            nv0 = *(const u16x8*)(vbase + (size_t)(ktn + srow) * 1024);
            nv1 = *(const u16x8*)(vbase + (size_t)(ktn + srow + 32) * 1024);
        }

        bf16x8 kf[4][2];
        #pragma unroll
        for (int n = 0; n < 4; ++n) {
            kf[n][0] = ldfrag(&lK[(n * 16 + l16) * 72 + quad * 8]);
            kf[n][1] = ldfrag(&lK[(n * 16 + l16) * 72 + 32 + quad * 8]);
        }
        f32x4 s[2][4];
        #pragma unroll
        for (int rg = 0; rg < 2; ++rg)
            #pragma unroll
            for (int n = 0; n < 4; ++n) {
                f32x4 t = {};
                t = mfma16(aq[rg][0], kf[n][0], t);
                t = mfma16(aq[rg][1], kf[n][1], t);
                s[rg][n] = t;
            }
        float bias[4];
        #pragma unroll
        for (int n = 0; n < 4; ++n)
            bias[n] = (kt + n * 16 + l16 < cn) ? 0.0f : -1e9f;
        #pragma unroll
        for (int rg = 0; rg < 2; ++rg)
            #pragma unroll
            for (int n = 0; n < 4; ++n)
                #pragma unroll
                for (int r = 0; r < 4; ++r) {
                    const float p =
                        __builtin_amdgcn_exp2f(__builtin_fmaf(s[rg][n][r], C, bias[n]));
                    ps_acc[rg][r] += p;
                    lP[(wave * 32 + rg * 16 + quad * 4 + r) * 72 + n * 16 + l16] =
                        f2bf_hw(p);
                }
        __asm__ __volatile__("s_waitcnt lgkmcnt(0)" ::: "memory");
        bf16x8 ap[2][2];
        #pragma unroll
        for (int rg = 0; rg < 2; ++rg) {
            ap[rg][0] = ldfrag(&lP[(wave * 32 + rg * 16 + l16) * 72 + quad * 8]);
            ap[rg][1] = ldfrag(&lP[(wave * 32 + rg * 16 + l16) * 72 + 32 + quad * 8]);
        }
        bf16x8 vf[4][2];
        #pragma unroll
        for (int ni = 0; ni < 4; ++ni) {
            vf[ni][0] = ldfrag(&lV[(ni * 16 + l16) * 72 + quad * 8]);
            vf[ni][1] = ldfrag(&lV[(ni * 16 + l16) * 72 + 32 + quad * 8]);
        }
        #pragma unroll
        for (int rg = 0; rg < 2; ++rg)
            #pragma unroll
            for (int ni = 0; ni < 4; ++ni) {
                o[rg][ni] = mfma16(ap[rg][0], vf[ni][0], o[rg][ni]);
                o[rg][ni] = mfma16(ap[rg][1], vf[ni][1], o[rg][ni]);
            }
    }
    #pragma unroll
    for (int off = 1; off < 16; off <<= 1)
        #pragma unroll
        for (int rg = 0; rg < 2; ++rg)
            #pragma unroll
            for (int r = 0; r < 4; ++r)
                ps_acc[rg][r] += __shfl_xor(ps_acc[rg][r], off);
    float rl[2][4];
    #pragma unroll
    for (int rg = 0; rg < 2; ++rg)
        #pragma unroll
        for (int r = 0; r < 4; ++r) rl[rg][r] = 1.f / ps_acc[rg][r];
    #pragma unroll
    for (int rg = 0; rg < 2; ++rg)
        #pragma unroll
        for (int ni = 0; ni < 4; ++ni)
            #pragma unroll
            for (int r = 0; r < 4; ++r) {
                const int row = q0 + wave * 32 + rg * 16 + quad * 4 + r;
                attb[(size_t)(bb * 1024 + row) * 1024 + h * 64 + ni * 16 + l16] =
                    f2bf_hw(o[rg][ni][r] * rl[rg][r]);
            }
}

// ---------- residual (bf16 y) + LayerNorm ----------
__global__ __launch_bounds__(256) void ln_res(const u16* __restrict__ ybf,
                                              const u16* __restrict__ xpb,
                                              const float* __restrict__ a2,
                                              const float* __restrict__ b2,
                                              float* __restrict__ out) {
    const int row = blockIdx.x, tid = threadIdx.x;
    const size_t base = (size_t)row * 1024;
    const int j = tid * 4;
    const u16x4 yv = *(const u16x4*)&ybf[base + j];
    const u16x4 xv = *(const u16x4*)&xpb[base + j];
    float x[4] = {bf2f(yv.x) + bf2f(xv.x), bf2f(yv.y) + bf2f(xv.y),
                  bf2f(yv.z) + bf2f(xv.z), bf2f(yv.w) + bf2f(xv.w)};
    float s = 0.f, ss = 0.f;
    #pragma unroll
    for (int i = 0; i < 4; ++i) { s += x[i]; ss += x[i] * x[i]; }
    #pragma unroll
    for (int off = 1; off < 64; off <<= 1) {
        s += __shfl_xor(s, off);
        ss += __shfl_xor(ss, off);
    }
    __shared__ float rs[4], rss[4];
    const int wave = tid >> 6, lane = tid & 63;
    if (lane == 0) { rs[wave] = s; rss[wave] = ss; }
    __syncthreads();
    s = rs[0] + rs[1] + rs[2] + rs[3];
    ss = rss[0] + rss[1] + rss[2] + rss[3];
    const float mean = s * (1.f / 1024.f);
    float var = (ss - s * mean) * (1.f / 1023.f);
    var = fmaxf(var, 0.f);
    const float inv = 1.f / (sqrtf(var) + 1e-6f);
    const float4 av = *(const float4*)&a2[j];
    const float4 bv = *(const float4*)&b2[j];
    float4 ov;
    ov.x = av.x * (x[0] - mean) * inv + bv.x;
    ov.y = av.y * (x[1] - mean) * inv + bv.y;
    ov.z = av.z * (x[2] - mean) * inv + bv.z;
    ov.w = av.w * (x[3] - mean) * inv + bv.w;
    *(float4*)&out[base + j] = ov;
}

extern "C" void kernel_launch(void* const* d_in, const int* in_sizes, int n_in,
                              void* d_out, int out_size, void* d_ws, size_t ws_size,
                              hipStream_t stream) {
    (void)in_sizes; (void)n_in; (void)out_size;
    const float* y   = (const float*)d_in[0];
    const int*   msk = (const int*)d_in[1];
    const float* Wq  = (const float*)d_in[2];
    const float* bq  = (const float*)d_in[3];
    const float* Wk  = (const float*)d_in[4];
    const float* bkb = (const float*)d_in[5];
    const float* Wv  = (const float*)d_in[6];
    const float* bv  = (const float*)d_in[7];
    const float* Wm  = (const float*)d_in[8];
    const float* bm  = (const float*)d_in[9];
    const float* a2  = (const float*)d_in[10];
    const float* b2  = (const float*)d_in[11];
    float* out = (float*)d_out;

    char* ws = (char*)d_ws;
    const size_t MB = 1u << 20;
    if (ws_size < 72 * MB) return;  // need 72 MB of scratch
    u16* yb  = (u16*)(ws);             // 16 MB, stays LIVE (ln_res reads it)
    u16* wqb = (u16*)(ws + 16 * MB);   // wq/wk/wv/wm contiguous (8 MB)
    u16* wmb = (u16*)(ws + 22 * MB);
    u16* qb  = (u16*)(ws + 24 * MB);   // 16 MB (reused as bf16 xp after attn)
    u16* kb  = (u16*)(ws + 40 * MB);   // 16 MB
    u16* vb  = (u16*)(ws + 56 * MB);   // 16 MB (attn reads it live)
    u16* xpb  = qb;   // qb dead after attn

    int* idxb = (int*)d_out;                       // 8 x 1024 ints
    int* cntb = idxb + 8192;                       // 8 ints
    u16* attb = (u16*)((char*)d_out + 16 * MB);    // 16 MB

    conv_all<<<12289, 256, 0, stream>>>(y, Wq, Wk, Wv, Wm, yb, wqb,
                                        msk, idxb, cntb);

    // fused Q + compacted-KV GEMM: 256 Q-blocks + 512 KV-blocks (dead ones
    // exit on cnt), now at 2 blocks/CU (80 KiB LDS). Wkv = wqb + 1M u16.
    gemm_qkv<<<dim3(768), 512, 0, stream>>>(
        yb, wqb, wqb + 1024 * 1024, bq, bkb, bv, qb, kb, vb, idxb, cntb);

    attn<<<dim3(1024), 256, 0, stream>>>(qb, kb, vb, cntb, attb);

    // M-proj: M=8192, N=1024, tile 256x128 -> 32x8 = 256 blocks = 1/CU
    gemm8b<<<dim3(256), 512, 0, stream>>>(
        attb, wmb, bm, bm, bm, xpb, xpb, xpb, 1024, 8);

    ln_res<<<8192, 256, 0, stream>>>(yb, xpb, a2, b2, out);
}

// Round 7
// 263.348 us; speedup vs baseline: 1.0653x; 1.0280x over previous
//
#include <hip/hip_runtime.h>

#define DEVFN __device__ __forceinline__

typedef unsigned short u16;
typedef __attribute__((ext_vector_type(8))) unsigned short u16x8;
typedef __attribute__((ext_vector_type(4))) unsigned short u16x4;
typedef __attribute__((ext_vector_type(8))) __bf16 bf16x8;
typedef __attribute__((ext_vector_type(4))) float f32x4;

// ---------- helpers ----------
DEVFN u16 f2bf_hw(float f) {  // hardware RNE convert (single v_cvt)
    return __builtin_bit_cast(u16, (__bf16)f);
}

DEVFN float bf2f(u16 h) {
    unsigned u = (unsigned)h << 16;
    return __builtin_bit_cast(float, u);
}

DEVFN bf16x8 ldfrag(const u16* p) {
    return __builtin_bit_cast(bf16x8, *(const u16x8*)p);
}

DEVFN f32x4 mfma16(bf16x8 a, bf16x8 b, f32x4 c) {
    return __builtin_amdgcn_mfma_f32_16x16x32_bf16(a, b, c, 0, 0, 0);
}

// async global->LDS, 16B per lane; l must be the wave-uniform base.
// The GLOBAL source address is per-lane (guide §5) -> row-gather OK.
DEVFN void async16(const u16* g, u16* l) {
    __builtin_amdgcn_global_load_lds(
        (const __attribute__((address_space(1))) void*)g,
        (__attribute__((address_space(3))) void*)l, 16, 0, 0);
}

// ---------- fp32->bf16 converts + mask compaction, ONE dispatch ----------
__global__ __launch_bounds__(256) void conv_all(const float* __restrict__ y,
                                                const float* __restrict__ w0,
                                                const float* __restrict__ w1,
                                                const float* __restrict__ w2,
                                                const float* __restrict__ w3,
                                                u16* __restrict__ yb,
                                                u16* __restrict__ wb,
                                                const int* __restrict__ mask,
                                                int* __restrict__ idx,
                                                int* __restrict__ cnt) {
    const int b = blockIdx.x;
    if (b >= 12288) {
        const int wave = threadIdx.x >> 6, lane = threadIdx.x & 63;
        for (int bb = wave; bb < 8; bb += 4) {
            const int* m = mask + bb * 1024;
            int* ib = idx + bb * 1024;
            int base = 0;
            for (int t = 0; t < 16; ++t) {
                const int pos = t * 64 + lane;
                const int valid = (m[pos] == 0) ? 1 : 0;
                const unsigned long long bal = __ballot(valid);
                const int pre = __popcll(bal & ((1ull << lane) - 1ull));
                if (valid) ib[base + pre] = pos;
                base += (int)__popcll(bal);
            }
            if (lane == 0) cnt[bb] = base;
            for (int i = base + lane; i < 1024; i += 64) ib[i] = 0;  // safe pad
        }
        return;
    }
    const float* src;
    u16* dst;
    int i;
    if (b < 8192) {
        src = y; dst = yb;
        i = b * 1024 + threadIdx.x * 4;
    } else {
        const int g = (b - 8192) >> 10;
        src = g == 0 ? w0 : (g == 1 ? w1 : (g == 2 ? w2 : w3));
        dst = wb + (size_t)g * 1024 * 1024;
        i = ((b - 8192) & 1023) * 1024 + threadIdx.x * 4;
    }
    const float4 v = *(const float4*)&src[i];
    u16x4 o;
    o.x = f2bf_hw(v.x); o.y = f2bf_hw(v.y);
    o.z = f2bf_hw(v.z); o.w = f2bf_hw(v.w);
    *(u16x4*)&dst[i] = o;
}

// ---------- Q + compacted-KV GEMM on the LEGACY 128^2 high-residency engine --
// Round-7: the 256-tile/512-thread family is a dead end (r1-r3,r6: 26-29%
// MfmaUtil, occupancy ~14-19%, 22-us/round quantization; r6's single-buffer B
// put load latency on the critical path). The ONLY engine with measured high
// residency + rate is round-0's 128x128 tile (56-60 VGPR, 16.5 KiB LDS ->
// 4 blocks/CU, 2.7 TF/CU busy, 1536 tiles in 75.6 us). r5 proved that engine
// is ORDER-sensitive (work-stealing +44%/tile), not gather-sensitive.
// => legacy engine + STATIC n-fast grid + KV compaction (34.4 GFLOP):
//    items 0..511   : Q  = y      @ Wq^T   (64 mtiles x 8 ntiles, n-fast)
//    items 512..1535: KV = y[idx] @ [Wk;Wv]^T per batch: 8 mtiles x 16
//                     ntiles, n-fast; tile alive iff m0 < cn (covers all
//                     rows < ceil128(cn) >= kEnd read by attn)
// ~1052 alive tiles on 1024 resident slots -> one packed round + small tail.
// Per-tile arithmetic/order identical to all rounds -> absmax bit-identical.
__global__ __launch_bounds__(256, 4) void gemm_qkv(const u16* __restrict__ A,
                                                   const u16* __restrict__ Wq,
                                                   const u16* __restrict__ Wkv,
                                                   const float* __restrict__ bq,
                                                   const float* __restrict__ bk,
                                                   const float* __restrict__ bv,
                                                   u16* __restrict__ qb,
                                                   u16* __restrict__ kb,
                                                   u16* __restrict__ vb,
                                                   const int* __restrict__ idxb,
                                                   const int* __restrict__ cntb) {
    const int K = 1024;
    __shared__ u16 lA[128 * 32];
    __shared__ u16 lB[128 * 32];
    const int tid = threadIdx.x;
    const int wave = tid >> 6, lane = tid & 63;
    const int quad = lane >> 4, l16 = lane & 15;
    const int wm = (wave >> 1) * 64, wn = (wave & 1) * 64;
    const int srow = tid >> 2, scol = (tid & 3) * 8;
    // ---- static decode (n-fast everywhere, Q first then KV batches) ----
    const int item = blockIdx.x;
    int m0, n0, rowbase = 0;
    const u16* Bt;
    const float *bp0, *bp1;
    u16 *cp0, *cp1;
    const int* ib = nullptr;
    if (item < 512) {  // Q: m = item>>3, n = item&7
        m0 = (item >> 3) * 128;
        n0 = (item & 7) * 128;
        Bt = Wq; bp0 = bq; bp1 = bq; cp0 = qb; cp1 = qb;
    } else {  // KV: batch-major, then m, n fastest
        const int t = item - 512;
        const int b = t >> 7, rem = t & 127;
        const int mb = rem >> 4, nb = rem & 15;
        const int cn = cntb[b];
        m0 = mb * 128;
        if (m0 >= cn) return;  // dead tile (rows >= ceil128(cn) never read)
        n0 = nb * 128;
        rowbase = b * 1024;
        ib = idxb + b * 1024;
        Bt = Wkv; bp0 = bk; bp1 = bv; cp0 = kb; cp1 = vb;
    }
    int r0 = m0 + srow, r1 = m0 + 64 + srow;
    if (ib) { r0 = ib[r0]; r1 = ib[r1]; }  // gather compacted A rows
    const u16* Ag0 = A + (size_t)(rowbase + r0) * K + scol;
    const u16* Ag1 = A + (size_t)(rowbase + r1) * K + scol;
    const u16* Bg0 = Bt + (size_t)(n0 + srow) * K + scol;
    const u16* Bg1 = Bt + (size_t)(n0 + 64 + srow) * K + scol;
    u16* lA0 = &lA[wave * 512];
    u16* lA1 = &lA[2048 + wave * 512];
    u16* lB0 = &lB[wave * 512];
    u16* lB1 = &lB[2048 + wave * 512];
    f32x4 acc[4][4] = {};
    for (int k0 = 0; k0 < K; k0 += 32) {
        __syncthreads();
        async16(Ag0 + k0, lA0);
        async16(Ag1 + k0, lA1);
        async16(Bg0 + k0, lB0);
        async16(Bg1 + k0, lB1);
        __syncthreads();
        bf16x8 af[4], bfr[4];
        #pragma unroll
        for (int i = 0; i < 4; ++i)
            af[i] = ldfrag(&lA[(wm + i * 16 + l16) * 32 + quad * 8]);
        #pragma unroll
        for (int i = 0; i < 4; ++i)
            bfr[i] = ldfrag(&lB[(wn + i * 16 + l16) * 32 + quad * 8]);
        #pragma unroll
        for (int mi = 0; mi < 4; ++mi)
            #pragma unroll
            for (int ni = 0; ni < 4; ++ni)
                acc[mi][ni] = mfma16(af[mi], bfr[ni], acc[mi][ni]);
    }
    // epilogue: bias + bf16 store; col>>10 selects {q} or {k,v}
    #pragma unroll
    for (int mi = 0; mi < 4; ++mi) {
        #pragma unroll
        for (int ni = 0; ni < 4; ++ni) {
            const int col = n0 + wn + ni * 16 + l16;
            const int cs = col >> 10;
            const int c = col & 1023;
            const float* bp = cs == 0 ? bp0 : bp1;
            u16* cp = cs == 0 ? cp0 : cp1;
            const float bb = bp[c];
            #pragma unroll
            for (int r = 0; r < 4; ++r) {
                const int row = m0 + wm + mi * 16 + quad * 4 + r;
                cp[(size_t)(rowbase + row) * 1024 + c] =
                    f2bf_hw(acc[mi][ni][r] + bb);
            }
        }
    }
}

// ---------- pipelined 256x128 GEMM (round-2 kernel, kept for M-proj) ----------
__global__ __launch_bounds__(512, 2) void gemm8b(const u16* __restrict__ A,
                                                 const u16* __restrict__ Bt,
                                                 const float* __restrict__ b0,
                                                 const float* __restrict__ b1,
                                                 const float* __restrict__ b2,
                                                 u16* __restrict__ C0,
                                                 u16* __restrict__ C1,
                                                 u16* __restrict__ C2,
                                                 int K, int NBX) {
    __shared__ u16 lds[2][24576];  // per buf: A @0 (16384), B @16384 (8192)
    const int NT = K >> 6;
    const int tid = threadIdx.x;
    const int wave = tid >> 6, lane = tid & 63;
    const int quad = lane >> 4, l16 = lane & 15;
    const int wm = wave >> 1, wn = wave & 1;
    const int nwg = gridDim.x, cpx = nwg >> 3;
    const int sb = (blockIdx.x & 7) * cpx + (blockIdx.x >> 3);
    const int bx = sb % NBX, by = sb / NBX;
    const int m0 = by * 256, n0 = bx * 128;
    const int sr = lane >> 3, sc = lane & 7;
    const int scs = (sc ^ sr) << 3;
    const u16* Ag = A + (size_t)(m0 + wave * 8 + sr) * K + scs;
    const u16* Bg = Bt + (size_t)(n0 + wave * 8 + sr) * K + scs;
    const size_t rstep = (size_t)64 * K;
    const int swz = (quad ^ (l16 & 7)) << 3;
    const int rofA = (wm * 64 + l16) * 64 + swz;
    const int rofB = (wn * 64 + l16) * 64 + swz;

#define STAGE(gp, lp)                                        \
    do {                                                     \
        async16((gp), (lp) + wave * 512);                    \
        async16((gp) + rstep, (lp) + 4096 + wave * 512);     \
    } while (0)

    f32x4 acc[4][4] = {};

    STAGE(Ag, &lds[0][0]);
    STAGE(Ag + 2 * rstep, &lds[0][8192]);
    STAGE(Bg, &lds[0][16384]);
    STAGE(Ag + 64, &lds[1][0]);
    STAGE(Ag + 2 * rstep + 64, &lds[1][8192]);
    asm volatile("s_waitcnt vmcnt(4)" ::: "memory");
    __builtin_amdgcn_s_barrier();

    for (int t = 0; t < NT; ++t) {
        const int buf = t & 1;
        const u16* Ar = &lds[buf][0];
        const u16* Br = &lds[buf][16384];
        bf16x8 af[4][2], bfr[4][2];
        #pragma unroll
        for (int mi = 0; mi < 4; ++mi) {
            af[mi][0] = ldfrag(Ar + mi * 1024 + rofA);
            af[mi][1] = ldfrag(Ar + mi * 1024 + (rofA ^ 32));
        }
        #pragma unroll
        for (int ni = 0; ni < 2; ++ni) {
            bfr[ni][0] = ldfrag(Br + ni * 1024 + rofB);
            bfr[ni][1] = ldfrag(Br + ni * 1024 + (rofB ^ 32));
        }
        if (t + 1 < NT) STAGE(Bg + (t + 1) * 64, &lds[buf ^ 1][16384]);
        __builtin_amdgcn_s_barrier();
        asm volatile("s_waitcnt lgkmcnt(0)" ::: "memory");
        __builtin_amdgcn_s_setprio(1);
        #pragma unroll
        for (int mi = 0; mi < 4; ++mi)
            #pragma unroll
            for (int ni = 0; ni < 2; ++ni) {
                acc[mi][ni] = mfma16(af[mi][0], bfr[ni][0], acc[mi][ni]);
                acc[mi][ni] = mfma16(af[mi][1], bfr[ni][1], acc[mi][ni]);
            }
        __builtin_amdgcn_s_setprio(0);
        __builtin_amdgcn_s_barrier();
        #pragma unroll
        for (int ni = 2; ni < 4; ++ni) {
            bfr[ni][0] = ldfrag(Br + ni * 1024 + rofB);
            bfr[ni][1] = ldfrag(Br + ni * 1024 + (rofB ^ 32));
        }
        if (t + 2 < NT) {
            STAGE(Ag + (t + 2) * 64, &lds[buf][0]);
            STAGE(Ag + 2 * rstep + (t + 2) * 64, &lds[buf][8192]);
        }
        __builtin_amdgcn_s_barrier();
        asm volatile("s_waitcnt lgkmcnt(0)" ::: "memory");
        __builtin_amdgcn_s_setprio(1);
        #pragma unroll
        for (int mi = 0; mi < 4; ++mi)
            #pragma unroll
            for (int ni = 2; ni < 4; ++ni) {
                acc[mi][ni] = mfma16(af[mi][0], bfr[ni][0], acc[mi][ni]);
                acc[mi][ni] = mfma16(af[mi][1], bfr[ni][1], acc[mi][ni]);
            }
        __builtin_amdgcn_s_setprio(0);
        if (t < NT - 2)
            asm volatile("s_waitcnt vmcnt(4)" ::: "memory");
        else
            asm volatile("s_waitcnt vmcnt(0)" ::: "memory");
        __builtin_amdgcn_s_barrier();
    }
#undef STAGE
    const int wrow = m0 + wm * 64 + quad * 4;
    #pragma unroll
    for (int ni = 0; ni < 4; ++ni) {
        const int col = n0 + wn * 64 + ni * 16 + l16;
        const int cs = col >> 10;
        const int c = col & 1023;
        const float* bp = cs == 0 ? b0 : (cs == 1 ? b1 : b2);
        u16* cp = cs == 0 ? C0 : (cs == 1 ? C1 : C2);
        const float bb = bp[c];
        #pragma unroll
        for (int mi = 0; mi < 4; ++mi)
            #pragma unroll
            for (int r = 0; r < 4; ++r) {
                const int row = wrow + mi * 16 + r;
                cp[(size_t)row * 1024 + c] = f2bf_hw(acc[mi][ni][r] + bb);
            }
    }
}

// ---------- flash attention over COMPACTED K/V (dense rows) ----------
__global__ __launch_bounds__(256) void attn(const u16* __restrict__ qb,
                                            const u16* __restrict__ kb,
                                            const u16* __restrict__ vb,
                                            const int* __restrict__ cntb,
                                            u16* __restrict__ attb) {
    const int lin = blockIdx.x;
    const int xcd = lin & 7, slot = lin >> 3;          // slot 0..127
    const int bh = xcd * 16 + (slot >> 3);
    const int q0 = (slot & 7) * 128;
    const int bb = bh >> 4, h = bh & 15;
    const int tid = threadIdx.x, wave = tid >> 6, lane = tid & 63;
    const int quad = lane >> 4, l16 = lane & 15;
    __shared__ u16 lK[64 * 72];
    __shared__ u16 lV[64 * 72];
    __shared__ u16 lP[128 * 72];

    const int cn = cntb[bb];
    const int kEnd = (cn + 63) & ~63;

    bf16x8 aq[2][2];
    #pragma unroll
    for (int rg = 0; rg < 2; ++rg) {
        const int qrow = q0 + wave * 32 + rg * 16 + l16;
        const u16* qp = qb + (size_t)(bb * 1024 + qrow) * 1024 + h * 64 + quad * 8;
        aq[rg][0] = ldfrag(qp);
        aq[rg][1] = ldfrag(qp + 32);
    }

    f32x4 o[2][4] = {};
    float ps_acc[2][4] = {};

    const int srow = tid >> 3, scol = (tid & 7) * 8;
    const u16* kbase = kb + (size_t)(bb * 1024) * 1024 + h * 64 + scol;
    const u16* vbase = vb + (size_t)(bb * 1024) * 1024 + h * 64 + scol;

    u16x8 nk0 = *(const u16x8*)(kbase + (size_t)srow * 1024);
    u16x8 nk1 = *(const u16x8*)(kbase + (size_t)(srow + 32) * 1024);
    u16x8 nv0 = *(const u16x8*)(vbase + (size_t)srow * 1024);
    u16x8 nv1 = *(const u16x8*)(vbase + (size_t)(srow + 32) * 1024);

    const float C = 0.18033688011112043f;  // 0.125 * log2(e)

    for (int kt = 0; kt < kEnd; kt += 64) {
        __syncthreads();
        *(u16x8*)&lK[srow * 72 + scol] = nk0;
        *(u16x8*)&lK[(srow + 32) * 72 + scol] = nk1;
        #pragma unroll
        for (int j = 0; j < 8; ++j) {
            lV[(scol + j) * 72 + srow] = nv0[j];
            lV[(scol + j) * 72 + srow + 32] = nv1[j];
        }
        __syncthreads();
        const int ktn = kt + 64;
        if (ktn < kEnd) {
            nk0 = *(const u16x8*)(kbase + (size_t)(ktn + srow) * 1024);
            nk1 = *(const u16x8*)(kbase + (size_t)(ktn + srow + 32) * 1024);
            nv0 = *(const u16x8*)(vbase + (size_t)(ktn + srow) * 1024);
            nv1 = *(const u16x8*)(vbase + (size_t)(ktn + srow + 32) * 1024);
        }

        bf16x8 kf[4][2];
        #pragma unroll
        for (int n = 0; n < 4; ++n) {
            kf[n][0] = ldfrag(&lK[(n * 16 + l16) * 72 + quad * 8]);
            kf[n][1] = ldfrag(&lK[(n * 16 + l16) * 72 + 32 + quad * 8]);
        }
        f32x4 s[2][4];
        #pragma unroll
        for (int rg = 0; rg < 2; ++rg)
            #pragma unroll
            for (int n = 0; n < 4; ++n) {
                f32x4 t = {};
                t = mfma16(aq[rg][0], kf[n][0], t);
                t = mfma16(aq[rg][1], kf[n][1], t);
                s[rg][n] = t;
            }
        float bias[4];
        #pragma unroll
        for (int n = 0; n < 4; ++n)
            bias[n] = (kt + n * 16 + l16 < cn) ? 0.0f : -1e9f;
        #pragma unroll
        for (int rg = 0; rg < 2; ++rg)
            #pragma unroll
            for (int n = 0; n < 4; ++n)
                #pragma unroll
                for (int r = 0; r < 4; ++r) {
                    const float p =
                        __builtin_amdgcn_exp2f(__builtin_fmaf(s[rg][n][r], C, bias[n]));
                    ps_acc[rg][r] += p;
                    lP[(wave * 32 + rg * 16 + quad * 4 + r) * 72 + n * 16 + l16] =
                        f2bf_hw(p);
                }
        __asm__ __volatile__("s_waitcnt lgkmcnt(0)" ::: "memory");
        bf16x8 ap[2][2];
        #pragma unroll
        for (int rg = 0; rg < 2; ++rg) {
            ap[rg][0] = ldfrag(&lP[(wave * 32 + rg * 16 + l16) * 72 + quad * 8]);
            ap[rg][1] = ldfrag(&lP[(wave * 32 + rg * 16 + l16) * 72 + 32 + quad * 8]);
        }
        bf16x8 vf[4][2];
        #pragma unroll
        for (int ni = 0; ni < 4; ++ni) {
            vf[ni][0] = ldfrag(&lV[(ni * 16 + l16) * 72 + quad * 8]);
            vf[ni][1] = ldfrag(&lV[(ni * 16 + l16) * 72 + 32 + quad * 8]);
        }
        #pragma unroll
        for (int rg = 0; rg < 2; ++rg)
            #pragma unroll
            for (int ni = 0; ni < 4; ++ni) {
                o[rg][ni] = mfma16(ap[rg][0], vf[ni][0], o[rg][ni]);
                o[rg][ni] = mfma16(ap[rg][1], vf[ni][1], o[rg][ni]);
            }
    }
    #pragma unroll
    for (int off = 1; off < 16; off <<= 1)
        #pragma unroll
        for (int rg = 0; rg < 2; ++rg)
            #pragma unroll
            for (int r = 0; r < 4; ++r)
                ps_acc[rg][r] += __shfl_xor(ps_acc[rg][r], off);
    float rl[2][4];
    #pragma unroll
    for (int rg = 0; rg < 2; ++rg)
        #pragma unroll
        for (int r = 0; r < 4; ++r) rl[rg][r] = 1.f / ps_acc[rg][r];
    #pragma unroll
    for (int rg = 0; rg < 2; ++rg)
        #pragma unroll
        for (int ni = 0; ni < 4; ++ni)
            #pragma unroll
            for (int r = 0; r < 4; ++r) {
                const int row = q0 + wave * 32 + rg * 16 + quad * 4 + r;
                attb[(size_t)(bb * 1024 + row) * 1024 + h * 64 + ni * 16 + l16] =
                    f2bf_hw(o[rg][ni][r] * rl[rg][r]);
            }
}

// ---------- residual (bf16 y) + LayerNorm ----------
__global__ __launch_bounds__(256) void ln_res(const u16* __restrict__ ybf,
                                              const u16* __restrict__ xpb,
                                              const float* __restrict__ a2,
                                              const float* __restrict__ b2,
                                              float* __restrict__ out) {
    const int row = blockIdx.x, tid = threadIdx.x;
    const size_t base = (size_t)row * 1024;
    const int j = tid * 4;
    const u16x4 yv = *(const u16x4*)&ybf[base + j];
    const u16x4 xv = *(const u16x4*)&xpb[base + j];
    float x[4] = {bf2f(yv.x) + bf2f(xv.x), bf2f(yv.y) + bf2f(xv.y),
                  bf2f(yv.z) + bf2f(xv.z), bf2f(yv.w) + bf2f(xv.w)};
    float s = 0.f, ss = 0.f;
    #pragma unroll
    for (int i = 0; i < 4; ++i) { s += x[i]; ss += x[i] * x[i]; }
    #pragma unroll
    for (int off = 1; off < 64; off <<= 1) {
        s += __shfl_xor(s, off);
        ss += __shfl_xor(ss, off);
    }
    __shared__ float rs[4], rss[4];
    const int wave = tid >> 6, lane = tid & 63;
    if (lane == 0) { rs[wave] = s; rss[wave] = ss; }
    __syncthreads();
    s = rs[0] + rs[1] + rs[2] + rs[3];
    ss = rss[0] + rss[1] + rss[2] + rss[3];
    const float mean = s * (1.f / 1024.f);
    float var = (ss - s * mean) * (1.f / 1023.f);
    var = fmaxf(var, 0.f);
    const float inv = 1.f / (sqrtf(var) + 1e-6f);
    const float4 av = *(const float4*)&a2[j];
    const float4 bv = *(const float4*)&b2[j];
    float4 ov;
    ov.x = av.x * (x[0] - mean) * inv + bv.x;
    ov.y = av.y * (x[1] - mean) * inv + bv.y;
    ov.z = av.z * (x[2] - mean) * inv + bv.z;
    ov.w = av.w * (x[3] - mean) * inv + bv.w;
    *(float4*)&out[base + j] = ov;
}

extern "C" void kernel_launch(void* const* d_in, const int* in_sizes, int n_in,
                              void* d_out, int out_size, void* d_ws, size_t ws_size,
                              hipStream_t stream) {
    (void)in_sizes; (void)n_in; (void)out_size;
    const float* y   = (const float*)d_in[0];
    const int*   msk = (const int*)d_in[1];
    const float* Wq  = (const float*)d_in[2];
    const float* bq  = (const float*)d_in[3];
    const float* Wk  = (const float*)d_in[4];
    const float* bkb = (const float*)d_in[5];
    const float* Wv  = (const float*)d_in[6];
    const float* bv  = (const float*)d_in[7];
    const float* Wm  = (const float*)d_in[8];
    const float* bm  = (const float*)d_in[9];
    const float* a2  = (const float*)d_in[10];
    const float* b2  = (const float*)d_in[11];
    float* out = (float*)d_out;

    char* ws = (char*)d_ws;
    const size_t MB = 1u << 20;
    if (ws_size < 72 * MB) return;  // need 72 MB of scratch
    u16* yb  = (u16*)(ws);             // 16 MB, stays LIVE (ln_res reads it)
    u16* wqb = (u16*)(ws + 16 * MB);   // wq/wk/wv/wm contiguous (8 MB)
    u16* wmb = (u16*)(ws + 22 * MB);
    u16* qb  = (u16*)(ws + 24 * MB);   // 16 MB (reused as bf16 xp after attn)
    u16* kb  = (u16*)(ws + 40 * MB);   // 16 MB
    u16* vb  = (u16*)(ws + 56 * MB);   // 16 MB (attn reads it live)
    u16* xpb  = qb;   // qb dead after attn

    int* idxb = (int*)d_out;                       // 8 x 1024 ints
    int* cntb = idxb + 8192;                       // 8 ints
    u16* attb = (u16*)((char*)d_out + 16 * MB);    // 16 MB

    conv_all<<<12289, 256, 0, stream>>>(y, Wq, Wk, Wv, Wm, yb, wqb,
                                        msk, idxb, cntb);

    // Q + compacted-KV on the legacy 4-blocks/CU engine: 512 Q-tiles +
    // 1024 KV-slots (dead tiles exit on cnt) -> ~1052 alive on 1024 slots.
    gemm_qkv<<<dim3(1536), 256, 0, stream>>>(
        yb, wqb, wqb + 1024 * 1024, bq, bkb, bv, qb, kb, vb, idxb, cntb);

    attn<<<dim3(1024), 256, 0, stream>>>(qb, kb, vb, cntb, attb);

    // M-proj: M=8192, N=1024, tile 256x128 -> 32x8 = 256 blocks = 1/CU
    gemm8b<<<dim3(256), 512, 0, stream>>>(
        attb, wmb, bm, bm, bm, xpb, xpb, xpb, 1024, 8);

    ln_res<<<8192, 256, 0, stream>>>(yb, xpb, a2, b2, out);
}

// Round 8
// 258.630 us; speedup vs baseline: 1.0848x; 1.0182x over previous
//
#include <hip/hip_runtime.h>

#define DEVFN __device__ __forceinline__

typedef unsigned short u16;
typedef __attribute__((ext_vector_type(8))) unsigned short u16x8;
typedef __attribute__((ext_vector_type(4))) unsigned short u16x4;
typedef __attribute__((ext_vector_type(8))) __bf16 bf16x8;
typedef __attribute__((ext_vector_type(4))) float f32x4;

// ---------- helpers ----------
DEVFN u16 f2bf_hw(float f) {  // hardware RNE convert (single v_cvt)
    return __builtin_bit_cast(u16, (__bf16)f);
}

DEVFN float bf2f(u16 h) {
    unsigned u = (unsigned)h << 16;
    return __builtin_bit_cast(float, u);
}

DEVFN bf16x8 ldfrag(const u16* p) {
    return __builtin_bit_cast(bf16x8, *(const u16x8*)p);
}

DEVFN f32x4 mfma16(bf16x8 a, bf16x8 b, f32x4 c) {
    return __builtin_amdgcn_mfma_f32_16x16x32_bf16(a, b, c, 0, 0, 0);
}

// async global->LDS, 16B per lane; l must be the wave-uniform base.
// The GLOBAL source address is per-lane (guide §5) -> row-gather OK.
DEVFN void async16(const u16* g, u16* l) {
    __builtin_amdgcn_global_load_lds(
        (const __attribute__((address_space(1))) void*)g,
        (__attribute__((address_space(3))) void*)l, 16, 0, 0);
}

// ---------- fp32->bf16 converts + mask compaction, ONE dispatch ----------
__global__ __launch_bounds__(256) void conv_all(const float* __restrict__ y,
                                                const float* __restrict__ w0,
                                                const float* __restrict__ w1,
                                                const float* __restrict__ w2,
                                                const float* __restrict__ w3,
                                                u16* __restrict__ yb,
                                                u16* __restrict__ wb,
                                                const int* __restrict__ mask,
                                                int* __restrict__ idx,
                                                int* __restrict__ cnt) {
    const int b = blockIdx.x;
    if (b >= 12288) {
        const int wave = threadIdx.x >> 6, lane = threadIdx.x & 63;
        for (int bb = wave; bb < 8; bb += 4) {
            const int* m = mask + bb * 1024;
            int* ib = idx + bb * 1024;
            int base = 0;
            for (int t = 0; t < 16; ++t) {
                const int pos = t * 64 + lane;
                const int valid = (m[pos] == 0) ? 1 : 0;
                const unsigned long long bal = __ballot(valid);
                const int pre = __popcll(bal & ((1ull << lane) - 1ull));
                if (valid) ib[base + pre] = pos;
                base += (int)__popcll(bal);
            }
            if (lane == 0) cnt[bb] = base;
            for (int i = base + lane; i < 1024; i += 64) ib[i] = 0;  // safe pad
        }
        return;
    }
    const float* src;
    u16* dst;
    int i;
    if (b < 8192) {
        src = y; dst = yb;
        i = b * 1024 + threadIdx.x * 4;
    } else {
        const int g = (b - 8192) >> 10;
        src = g == 0 ? w0 : (g == 1 ? w1 : (g == 2 ? w2 : w3));
        dst = wb + (size_t)g * 1024 * 1024;
        i = ((b - 8192) & 1023) * 1024 + threadIdx.x * 4;
    }
    const float4 v = *(const float4*)&src[i];
    u16x4 o;
    o.x = f2bf_hw(v.x); o.y = f2bf_hw(v.y);
    o.z = f2bf_hw(v.z); o.w = f2bf_hw(v.w);
    *(u16x4*)&dst[i] = o;
}

// ---------- Q + compacted-KV GEMM, legacy 128^2 engine + slot-XOR deconflict --
// Round-8: r7 (this engine, static n-fast grid, compaction) = 61 us, best.
// Remaining in-kernel waste: SQ_LDS_BANK_CONFLICT = 4.33M cyc (~17 kcyc/CU).
// Legacy [128][32]-u16 LDS: ds_read_b128 start-bank = (16*row+4*quad)%32 ->
// few start banks across l16 -> 4-8-way serialization. Fix = r2-proven
// both-sides slot-XOR (rule 21): 4 x 16B slots per row, perm p(row) =
// (row>>1)&3 (chosen so (row&1, quad^p) covers all 8 start banks exactly
// 2x per quad -> 2-way aliasing = free, m136). Write side: pre-swizzled
// per-lane GLOBAL col, linear LDS dest (gload_lds constraint); read side:
// slot = quad ^ ((l16>>1)&3). Same instruction count/schedule; fragments
// land in identical registers -> bit-identical output.
// Decode unchanged from r7:
//   items 0..511   : Q  = y      @ Wq^T   (64 mtiles x 8 ntiles, n-fast)
//   items 512..1535: KV = y[idx] @ [Wk;Wv]^T per batch (8 mtile-slots x 16,
//                    alive iff m0 < cn; covers [0, ceil128(cn)) >= kEnd)
__global__ __launch_bounds__(256, 4) void gemm_qkv(const u16* __restrict__ A,
                                                   const u16* __restrict__ Wq,
                                                   const u16* __restrict__ Wkv,
                                                   const float* __restrict__ bq,
                                                   const float* __restrict__ bk,
                                                   const float* __restrict__ bv,
                                                   u16* __restrict__ qb,
                                                   u16* __restrict__ kb,
                                                   u16* __restrict__ vb,
                                                   const int* __restrict__ idxb,
                                                   const int* __restrict__ cntb) {
    const int K = 1024;
    __shared__ u16 lA[128 * 32];
    __shared__ u16 lB[128 * 32];
    const int tid = threadIdx.x;
    const int wave = tid >> 6, lane = tid & 63;
    const int quad = lane >> 4, l16 = lane & 15;
    const int wm = (wave >> 1) * 64, wn = (wave & 1) * 64;
    const int srow = tid >> 2;
    // pre-swizzled source slot (write side of the slot-XOR)
    const int scol = (((tid & 3) ^ ((srow >> 1) & 3))) * 8;
    // ---- static decode (n-fast everywhere, Q first then KV batches) ----
    const int item = blockIdx.x;
    int m0, n0, rowbase = 0;
    const u16* Bt;
    const float *bp0, *bp1;
    u16 *cp0, *cp1;
    const int* ib = nullptr;
    if (item < 512) {  // Q: m = item>>3, n = item&7
        m0 = (item >> 3) * 128;
        n0 = (item & 7) * 128;
        Bt = Wq; bp0 = bq; bp1 = bq; cp0 = qb; cp1 = qb;
    } else {  // KV: batch-major, then m, n fastest
        const int t = item - 512;
        const int b = t >> 7, rem = t & 127;
        const int mb = rem >> 4, nb = rem & 15;
        const int cn = cntb[b];
        m0 = mb * 128;
        if (m0 >= cn) return;  // dead tile (rows >= ceil128(cn) never read)
        n0 = nb * 128;
        rowbase = b * 1024;
        ib = idxb + b * 1024;
        Bt = Wkv; bp0 = bk; bp1 = bv; cp0 = kb; cp1 = vb;
    }
    int r0 = m0 + srow, r1 = m0 + 64 + srow;
    if (ib) { r0 = ib[r0]; r1 = ib[r1]; }  // gather compacted A rows
    const u16* Ag0 = A + (size_t)(rowbase + r0) * K + scol;
    const u16* Ag1 = A + (size_t)(rowbase + r1) * K + scol;
    const u16* Bg0 = Bt + (size_t)(n0 + srow) * K + scol;
    const u16* Bg1 = Bt + (size_t)(n0 + 64 + srow) * K + scol;
    u16* lA0 = &lA[wave * 512];
    u16* lA1 = &lA[2048 + wave * 512];
    u16* lB0 = &lB[wave * 512];
    u16* lB1 = &lB[2048 + wave * 512];
    // read-side swizzled slot: row = (wm|wn) + i*16 + l16 -> (row>>1)&3 =
    // (l16>>1)&3 (wm/wn and i*16 are multiples of 16)
    const int sl = (quad ^ ((l16 >> 1) & 3)) * 8;
    f32x4 acc[4][4] = {};
    for (int k0 = 0; k0 < K; k0 += 32) {
        __syncthreads();
        async16(Ag0 + k0, lA0);
        async16(Ag1 + k0, lA1);
        async16(Bg0 + k0, lB0);
        async16(Bg1 + k0, lB1);
        __syncthreads();
        bf16x8 af[4], bfr[4];
        #pragma unroll
        for (int i = 0; i < 4; ++i)
            af[i] = ldfrag(&lA[(wm + i * 16 + l16) * 32 + sl]);
        #pragma unroll
        for (int i = 0; i < 4; ++i)
            bfr[i] = ldfrag(&lB[(wn + i * 16 + l16) * 32 + sl]);
        #pragma unroll
        for (int mi = 0; mi < 4; ++mi)
            #pragma unroll
            for (int ni = 0; ni < 4; ++ni)
                acc[mi][ni] = mfma16(af[mi], bfr[ni], acc[mi][ni]);
    }
    // epilogue: bias + bf16 store; col>>10 selects {q} or {k,v}
    #pragma unroll
    for (int mi = 0; mi < 4; ++mi) {
        #pragma unroll
        for (int ni = 0; ni < 4; ++ni) {
            const int col = n0 + wn + ni * 16 + l16;
            const int cs = col >> 10;
            const int c = col & 1023;
            const float* bp = cs == 0 ? bp0 : bp1;
            u16* cp = cs == 0 ? cp0 : cp1;
            const float bb = bp[c];
            #pragma unroll
            for (int r = 0; r < 4; ++r) {
                const int row = m0 + wm + mi * 16 + quad * 4 + r;
                cp[(size_t)(rowbase + row) * 1024 + c] =
                    f2bf_hw(acc[mi][ni][r] + bb);
            }
        }
    }
}

// ---------- pipelined 256x128 GEMM (round-2 kernel, kept for M-proj) ----------
__global__ __launch_bounds__(512, 2) void gemm8b(const u16* __restrict__ A,
                                                 const u16* __restrict__ Bt,
                                                 const float* __restrict__ b0,
                                                 const float* __restrict__ b1,
                                                 const float* __restrict__ b2,
                                                 u16* __restrict__ C0,
                                                 u16* __restrict__ C1,
                                                 u16* __restrict__ C2,
                                                 int K, int NBX) {
    __shared__ u16 lds[2][24576];  // per buf: A @0 (16384), B @16384 (8192)
    const int NT = K >> 6;
    const int tid = threadIdx.x;
    const int wave = tid >> 6, lane = tid & 63;
    const int quad = lane >> 4, l16 = lane & 15;
    const int wm = wave >> 1, wn = wave & 1;
    const int nwg = gridDim.x, cpx = nwg >> 3;
    const int sb = (blockIdx.x & 7) * cpx + (blockIdx.x >> 3);
    const int bx = sb % NBX, by = sb / NBX;
    const int m0 = by * 256, n0 = bx * 128;
    const int sr = lane >> 3, sc = lane & 7;
    const int scs = (sc ^ sr) << 3;
    const u16* Ag = A + (size_t)(m0 + wave * 8 + sr) * K + scs;
    const u16* Bg = Bt + (size_t)(n0 + wave * 8 + sr) * K + scs;
    const size_t rstep = (size_t)64 * K;
    const int swz = (quad ^ (l16 & 7)) << 3;
    const int rofA = (wm * 64 + l16) * 64 + swz;
    const int rofB = (wn * 64 + l16) * 64 + swz;

#define STAGE(gp, lp)                                        \
    do {                                                     \
        async16((gp), (lp) + wave * 512);                    \
        async16((gp) + rstep, (lp) + 4096 + wave * 512);     \
    } while (0)

    f32x4 acc[4][4] = {};

    STAGE(Ag, &lds[0][0]);
    STAGE(Ag + 2 * rstep, &lds[0][8192]);
    STAGE(Bg, &lds[0][16384]);
    STAGE(Ag + 64, &lds[1][0]);
    STAGE(Ag + 2 * rstep + 64, &lds[1][8192]);
    asm volatile("s_waitcnt vmcnt(4)" ::: "memory");
    __builtin_amdgcn_s_barrier();

    for (int t = 0; t < NT; ++t) {
        const int buf = t & 1;
        const u16* Ar = &lds[buf][0];
        const u16* Br = &lds[buf][16384];
        bf16x8 af[4][2], bfr[4][2];
        #pragma unroll
        for (int mi = 0; mi < 4; ++mi) {
            af[mi][0] = ldfrag(Ar + mi * 1024 + rofA);
            af[mi][1] = ldfrag(Ar + mi * 1024 + (rofA ^ 32));
        }
        #pragma unroll
        for (int ni = 0; ni < 2; ++ni) {
            bfr[ni][0] = ldfrag(Br + ni * 1024 + rofB);
            bfr[ni][1] = ldfrag(Br + ni * 1024 + (rofB ^ 32));
        }
        if (t + 1 < NT) STAGE(Bg + (t + 1) * 64, &lds[buf ^ 1][16384]);
        __builtin_amdgcn_s_barrier();
        asm volatile("s_waitcnt lgkmcnt(0)" ::: "memory");
        __builtin_amdgcn_s_setprio(1);
        #pragma unroll
        for (int mi = 0; mi < 4; ++mi)
            #pragma unroll
            for (int ni = 0; ni < 2; ++ni) {
                acc[mi][ni] = mfma16(af[mi][0], bfr[ni][0], acc[mi][ni]);
                acc[mi][ni] = mfma16(af[mi][1], bfr[ni][1], acc[mi][ni]);
            }
        __builtin_amdgcn_s_setprio(0);
        __builtin_amdgcn_s_barrier();
        #pragma unroll
        for (int ni = 2; ni < 4; ++ni) {
            bfr[ni][0] = ldfrag(Br + ni * 1024 + rofB);
            bfr[ni][1] = ldfrag(Br + ni * 1024 + (rofB ^ 32));
        }
        if (t + 2 < NT) {
            STAGE(Ag + (t + 2) * 64, &lds[buf][0]);
            STAGE(Ag + 2 * rstep + (t + 2) * 64, &lds[buf][8192]);
        }
        __builtin_amdgcn_s_barrier();
        asm volatile("s_waitcnt lgkmcnt(0)" ::: "memory");
        __builtin_amdgcn_s_setprio(1);
        #pragma unroll
        for (int mi = 0; mi < 4; ++mi)
            #pragma unroll
            for (int ni = 2; ni < 4; ++ni) {
                acc[mi][ni] = mfma16(af[mi][0], bfr[ni][0], acc[mi][ni]);
                acc[mi][ni] = mfma16(af[mi][1], bfr[ni][1], acc[mi][ni]);
            }
        __builtin_amdgcn_s_setprio(0);
        if (t < NT - 2)
            asm volatile("s_waitcnt vmcnt(4)" ::: "memory");
        else
            asm volatile("s_waitcnt vmcnt(0)" ::: "memory");
        __builtin_amdgcn_s_barrier();
    }
#undef STAGE
    const int wrow = m0 + wm * 64 + quad * 4;
    #pragma unroll
    for (int ni = 0; ni < 4; ++ni) {
        const int col = n0 + wn * 64 + ni * 16 + l16;
        const int cs = col >> 10;
        const int c = col & 1023;
        const float* bp = cs == 0 ? b0 : (cs == 1 ? b1 : b2);
        u16* cp = cs == 0 ? C0 : (cs == 1 ? C1 : C2);
        const float bb = bp[c];
        #pragma unroll
        for (int mi = 0; mi < 4; ++mi)
            #pragma unroll
            for (int r = 0; r < 4; ++r) {
                const int row = wrow + mi * 16 + r;
                cp[(size_t)row * 1024 + c] = f2bf_hw(acc[mi][ni][r] + bb);
            }
    }
}

// ---------- flash attention over COMPACTED K/V (dense rows) ----------
__global__ __launch_bounds__(256) void attn(const u16* __restrict__ qb,
                                            const u16* __restrict__ kb,
                                            const u16* __restrict__ vb,
                                            const int* __restrict__ cntb,
                                            u16* __restrict__ attb) {
    const int lin = blockIdx.x;
    const int xcd = lin & 7, slot = lin >> 3;          // slot 0..127
    const int bh = xcd * 16 + (slot >> 3);
    const int q0 = (slot & 7) * 128;
    const int bb = bh >> 4, h = bh & 15;
    const int tid = threadIdx.x, wave = tid >> 6, lane = tid & 63;
    const int quad = lane >> 4, l16 = lane & 15;
    __shared__ u16 lK[64 * 72];
    __shared__ u16 lV[64 * 72];
    __shared__ u16 lP[128 * 72];

    const int cn = cntb[bb];
    const int kEnd = (cn + 63) & ~63;

    bf16x8 aq[2][2];
    #pragma unroll
    for (int rg = 0; rg < 2; ++rg) {
        const int qrow = q0 + wave * 32 + rg * 16 + l16;
        const u16* qp = qb + (size_t)(bb * 1024 + qrow) * 1024 + h * 64 + quad * 8;
        aq[rg][0] = ldfrag(qp);
        aq[rg][1] = ldfrag(qp + 32);
    }

    f32x4 o[2][4] = {};
    float ps_acc[2][4] = {};

    const int srow = tid >> 3, scol = (tid & 7) * 8;
    const u16* kbase = kb + (size_t)(bb * 1024) * 1024 + h * 64 + scol;
    const u16* vbase = vb + (size_t)(bb * 1024) * 1024 + h * 64 + scol;

    u16x8 nk0 = *(const u16x8*)(kbase + (size_t)srow * 1024);
    u16x8 nk1 = *(const u16x8*)(kbase + (size_t)(srow + 32) * 1024);
    u16x8 nv0 = *(const u16x8*)(vbase + (size_t)srow * 1024);
    u16x8 nv1 = *(const u16x8*)(vbase + (size_t)(srow + 32) * 1024);

    const float C = 0.18033688011112043f;  // 0.125 * log2(e)

    for (int kt = 0; kt < kEnd; kt += 64) {
        __syncthreads();
        *(u16x8*)&lK[srow * 72 + scol] = nk0;
        *(u16x8*)&lK[(srow + 32) * 72 + scol] = nk1;
        #pragma unroll
        for (int j = 0; j < 8; ++j) {
            lV[(scol + j) * 72 + srow] = nv0[j];
            lV[(scol + j) * 72 + srow + 32] = nv1[j];
        }
        __syncthreads();
        const int ktn = kt + 64;
        if (ktn < kEnd) {
            nk0 = *(const u16x8*)(kbase + (size_t)(ktn + srow) * 1024);
            nk1 = *(const u16x8*)(kbase + (size_t)(ktn + srow + 32) * 1024);
            nv0 = *(const u16x8*)(vbase + (size_t)(ktn + srow) * 1024);
            nv1 = *(const u16x8*)(vbase + (size_t)(ktn + srow + 32) * 1024);
        }

        bf16x8 kf[4][2];
        #pragma unroll
        for (int n = 0; n < 4; ++n) {
            kf[n][0] = ldfrag(&lK[(n * 16 + l16) * 72 + quad * 8]);
            kf[n][1] = ldfrag(&lK[(n * 16 + l16) * 72 + 32 + quad * 8]);
        }
        f32x4 s[2][4];
        #pragma unroll
        for (int rg = 0; rg < 2; ++rg)
            #pragma unroll
            for (int n = 0; n < 4; ++n) {
                f32x4 t = {};
                t = mfma16(aq[rg][0], kf[n][0], t);
                t = mfma16(aq[rg][1], kf[n][1], t);
                s[rg][n] = t;
            }
        float bias[4];
        #pragma unroll
        for (int n = 0; n < 4; ++n)
            bias[n] = (kt + n * 16 + l16 < cn) ? 0.0f : -1e9f;
        #pragma unroll
        for (int rg = 0; rg < 2; ++rg)
            #pragma unroll
            for (int n = 0; n < 4; ++n)
                #pragma unroll
                for (int r = 0; r < 4; ++r) {
                    const float p =
                        __builtin_amdgcn_exp2f(__builtin_fmaf(s[rg][n][r], C, bias[n]));
                    ps_acc[rg][r] += p;
                    lP[(wave * 32 + rg * 16 + quad * 4 + r) * 72 + n * 16 + l16] =
                        f2bf_hw(p);
                }
        __asm__ __volatile__("s_waitcnt lgkmcnt(0)" ::: "memory");
        bf16x8 ap[2][2];
        #pragma unroll
        for (int rg = 0; rg < 2; ++rg) {
            ap[rg][0] = ldfrag(&lP[(wave * 32 + rg * 16 + l16) * 72 + quad * 8]);
            ap[rg][1] = ldfrag(&lP[(wave * 32 + rg * 16 + l16) * 72 + 32 + quad * 8]);
        }
        bf16x8 vf[4][2];
        #pragma unroll
        for (int ni = 0; ni < 4; ++ni) {
            vf[ni][0] = ldfrag(&lV[(ni * 16 + l16) * 72 + quad * 8]);
            vf[ni][1] = ldfrag(&lV[(ni * 16 + l16) * 72 + 32 + quad * 8]);
        }
        #pragma unroll
        for (int rg = 0; rg < 2; ++rg)
            #pragma unroll
            for (int ni = 0; ni < 4; ++ni) {
                o[rg][ni] = mfma16(ap[rg][0], vf[ni][0], o[rg][ni]);
                o[rg][ni] = mfma16(ap[rg][1], vf[ni][1], o[rg][ni]);
            }
    }
    #pragma unroll
    for (int off = 1; off < 16; off <<= 1)
        #pragma unroll
        for (int rg = 0; rg < 2; ++rg)
            #pragma unroll
            for (int r = 0; r < 4; ++r)
                ps_acc[rg][r] += __shfl_xor(ps_acc[rg][r], off);
    float rl[2][4];
    #pragma unroll
    for (int rg = 0; rg < 2; ++rg)
        #pragma unroll
        for (int r = 0; r < 4; ++r) rl[rg][r] = 1.f / ps_acc[rg][r];
    #pragma unroll
    for (int rg = 0; rg < 2; ++rg)
        #pragma unroll
        for (int ni = 0; ni < 4; ++ni)
            #pragma unroll
            for (int r = 0; r < 4; ++r) {
                const int row = q0 + wave * 32 + rg * 16 + quad * 4 + r;
                attb[(size_t)(bb * 1024 + row) * 1024 + h * 64 + ni * 16 + l16] =
                    f2bf_hw(o[rg][ni][r] * rl[rg][r]);
            }
}

// ---------- residual (bf16 y) + LayerNorm ----------
__global__ __launch_bounds__(256) void ln_res(const u16* __restrict__ ybf,
                                              const u16* __restrict__ xpb,
                                              const float* __restrict__ a2,
                                              const float* __restrict__ b2,
                                              float* __restrict__ out) {
    const int row = blockIdx.x, tid = threadIdx.x;
    const size_t base = (size_t)row * 1024;
    const int j = tid * 4;
    const u16x4 yv = *(const u16x4*)&ybf[base + j];
    const u16x4 xv = *(const u16x4*)&xpb[base + j];
    float x[4] = {bf2f(yv.x) + bf2f(xv.x), bf2f(yv.y) + bf2f(xv.y),
                  bf2f(yv.z) + bf2f(xv.z), bf2f(yv.w) + bf2f(xv.w)};
    float s = 0.f, ss = 0.f;
    #pragma unroll
    for (int i = 0; i < 4; ++i) { s += x[i]; ss += x[i] * x[i]; }
    #pragma unroll
    for (int off = 1; off < 64; off <<= 1) {
        s += __shfl_xor(s, off);
        ss += __shfl_xor(ss, off);
    }
    __shared__ float rs[4], rss[4];
    const int wave = tid >> 6, lane = tid & 63;
    if (lane == 0) { rs[wave] = s; rss[wave] = ss; }
    __syncthreads();
    s = rs[0] + rs[1] + rs[2] + rs[3];
    ss = rss[0] + rss[1] + rss[2] + rss[3];
    const float mean = s * (1.f / 1024.f);
    float var = (ss - s * mean) * (1.f / 1023.f);
    var = fmaxf(var, 0.f);
    const float inv = 1.f / (sqrtf(var) + 1e-6f);
    const float4 av = *(const float4*)&a2[j];
    const float4 bv = *(const float4*)&b2[j];
    float4 ov;
    ov.x = av.x * (x[0] - mean) * inv + bv.x;
    ov.y = av.y * (x[1] - mean) * inv + bv.y;
    ov.z = av.z * (x[2] - mean) * inv + bv.z;
    ov.w = av.w * (x[3] - mean) * inv + bv.w;
    *(float4*)&out[base + j] = ov;
}

extern "C" void kernel_launch(void* const* d_in, const int* in_sizes, int n_in,
                              void* d_out, int out_size, void* d_ws, size_t ws_size,
                              hipStream_t stream) {
    (void)in_sizes; (void)n_in; (void)out_size;
    const float* y   = (const float*)d_in[0];
    const int*   msk = (const int*)d_in[1];
    const float* Wq  = (const float*)d_in[2];
    const float* bq  = (const float*)d_in[3];
    const float* Wk  = (const float*)d_in[4];
    const float* bkb = (const float*)d_in[5];
    const float* Wv  = (const float*)d_in[6];
    const float* bv  = (const float*)d_in[7];
    const float* Wm  = (const float*)d_in[8];
    const float* bm  = (const float*)d_in[9];
    const float* a2  = (const float*)d_in[10];
    const float* b2  = (const float*)d_in[11];
    float* out = (float*)d_out;

    char* ws = (char*)d_ws;
    const size_t MB = 1u << 20;
    if (ws_size < 72 * MB) return;  // need 72 MB of scratch
    u16* yb  = (u16*)(ws);             // 16 MB, stays LIVE (ln_res reads it)
    u16* wqb = (u16*)(ws + 16 * MB);   // wq/wk/wv/wm contiguous (8 MB)
    u16* wmb = (u16*)(ws + 22 * MB);
    u16* qb  = (u16*)(ws + 24 * MB);   // 16 MB (reused as bf16 xp after attn)
    u16* kb  = (u16*)(ws + 40 * MB);   // 16 MB
    u16* vb  = (u16*)(ws + 56 * MB);   // 16 MB (attn reads it live)
    u16* xpb  = qb;   // qb dead after attn

    int* idxb = (int*)d_out;                       // 8 x 1024 ints
    int* cntb = idxb + 8192;                       // 8 ints
    u16* attb = (u16*)((char*)d_out + 16 * MB);    // 16 MB

    conv_all<<<12289, 256, 0, stream>>>(y, Wq, Wk, Wv, Wm, yb, wqb,
                                        msk, idxb, cntb);

    // Q + compacted-KV on the legacy 4-blocks/CU engine (slot-XOR deconflicted)
    gemm_qkv<<<dim3(1536), 256, 0, stream>>>(
        yb, wqb, wqb + 1024 * 1024, bq, bkb, bv, qb, kb, vb, idxb, cntb);

    attn<<<dim3(1024), 256, 0, stream>>>(qb, kb, vb, cntb, attb);

    // M-proj: M=8192, N=1024, tile 256x128 -> 32x8 = 256 blocks = 1/CU
    gemm8b<<<dim3(256), 512, 0, stream>>>(
        attb, wmb, bm, bm, bm, xpb, xpb, xpb, 1024, 8);

    ln_res<<<8192, 256, 0, stream>>>(yb, xpb, a2, b2, out);
}